// Round 8
// baseline (708.575 us; speedup 1.0000x reference)
//
#include <hip/hip_runtime.h>
#include <hip/hip_bf16.h>

// GCN: 3x GCNConv(relu) -> mean over layers -> global mean pool -> linear -> softmax
// N=100000, E=3200000, F_IN=128, F_HID=64, F_OUT=10, G=1000.
//
// out[dst] = dinv[dst] * ( sum_{e: row[e]=dst} z[col[e]] + z[dst] ) + b,
// z = (x @ W) * dinv[:,None], dinv = rsqrt(deg_col + 1).
//
// R18: R17 (fewer VMEM+VALU instrs) was NEUTRAL -> aggregate is bound by the
// memory machine on random gathers: Z (12.8MB) misses the 4MB per-XCD L2,
// random line requests eat L3 latency through a limited miss queue.
// Fix: PANEL-MAJOR Z and x-layers. 4 feature panels x 32B/node (3.2MB < 4MB
// L2). aggregate: panel = blockIdx.x / NBLK (panel-0 blocks dispatch first ->
// approximate global phase ordering); per phase the panel is L2-resident on
// every XCD, random gathers become L2 hits, fills become streaming.
// gemm/pool get panel address math; bin_edges_sort/build_csr unchanged.

#define ALIGN_UP(x, a) (((x) + (a) - 1) / (a) * (a))
#define NBMAX 256        // max buckets (node id >> 9), supports n <= 131072
#define CHUNK 12500      // max edges per bin block (13 regs/thread, fits LDS)

typedef float vfloat2 __attribute__((ext_vector_type(2)));

__device__ __forceinline__ float bf16_to_f32(unsigned short u) {
    return __uint_as_float(((unsigned)u) << 16);
}
__device__ __forceinline__ float bf16_lo(unsigned u) {
    return __uint_as_float(u << 16);
}
__device__ __forceinline__ float bf16_hi(unsigned u) {
    return __uint_as_float(u & 0xffff0000u);
}
__device__ __forceinline__ unsigned pack_bf16(float a, float b) {
    union { __hip_bfloat16 h; unsigned short u; } ua, ub;
    ua.h = __float2bfloat16(a); ub.h = __float2bfloat16(b);
    return (unsigned)ua.u | ((unsigned)ub.u << 16);
}

// ---------------- Pass A: LDS radix-partition of edges into 512-node buckets ----
// RB entry = (col<<9)|(row&511); CB entry = ushort col&511.
__global__ __launch_bounds__(1024, 8) void bin_edges_sort(const int* __restrict__ row,
                                                          const int* __restrict__ col,
                                                          int E, int NB, int bcap,
                                                          int* __restrict__ fillR,
                                                          int* __restrict__ fillC,
                                                          unsigned int* __restrict__ RB,
                                                          unsigned short* __restrict__ CB) {
    __shared__ unsigned int sortB[CHUNK + 44];     // 50KB; reused as ushort for C
    __shared__ int cntR[NBMAX], cntC[NBMAX];       // histogram, then scatter cursors
    __shared__ int offR[NBMAX + 1], offC[NBMAX + 1];
    __shared__ int baseR[NBMAX], baseC[NBMAX];
    __shared__ int wsumR[4], wsumC[4];

    int t = threadIdx.x;
    for (int i = t; i < NBMAX; i += 1024) { cntR[i] = 0; cntC[i] = 0; }
    __syncthreads();

    int per = (E + gridDim.x - 1) / gridDim.x;     // <= CHUNK by grid sizing
    int e0 = blockIdx.x * per, e1 = min(E, e0 + per);
    int m = e1 - e0;

    // load chunk ONCE into registers (fully unrolled -> static indexing)
    int r[13], c[13];
    #pragma unroll
    for (int k = 0; k < 13; k++) {
        int e = e0 + t + (k << 10);
        bool ok = e < e1;
        r[k] = ok ? row[e] : -1;
        c[k] = ok ? col[e] : 0;
    }
    // histogram
    #pragma unroll
    for (int k = 0; k < 13; k++) {
        if (r[k] >= 0) {
            atomicAdd(&cntR[r[k] >> 9], 1);
            atomicAdd(&cntC[c[k] >> 9], 1);
        }
    }
    __syncthreads();

    // parallel exclusive scans over 256 counters: waves 0-3 -> R, waves 4-7 -> C
    int idx = t & 255;
    bool isR = t < 256, isC = (t >= 256) && (t < 512);
    int val = isR ? cntR[idx] : (isC ? cntC[idx] : 0);
    int lane = t & 63, w4 = (t >> 6) & 3;
    int x = val;
    #pragma unroll
    for (int off = 1; off < 64; off <<= 1) {
        int y = __shfl_up(x, off, 64);
        if (lane >= off) x += y;
    }
    if (isR && lane == 63) wsumR[w4] = x;
    if (isC && lane == 63) wsumC[w4] = x;
    __syncthreads();
    if (isR) {
        int wb = 0;
        #pragma unroll
        for (int i = 0; i < 4; i++) if (i < w4) wb += wsumR[i];
        offR[idx] = wb + x - val;
        if (idx < NB) baseR[idx] = val ? atomicAdd(&fillR[idx], val) : 0;
    }
    if (isC) {
        int wb = 0;
        #pragma unroll
        for (int i = 0; i < 4; i++) if (i < w4) wb += wsumC[i];
        offC[idx] = wb + x - val;
        if (idx < NB) baseC[idx] = val ? atomicAdd(&fillC[idx], val) : 0;
    }
    if (t == 0) offR[NBMAX] = m;
    if (t == 1) offC[NBMAX] = m;
    __syncthreads();
    for (int i = t; i < NBMAX; i += 1024) { cntR[i] = 0; cntC[i] = 0; }  // -> cursors
    __syncthreads();

    // ---- row side: scatter into LDS-sorted order, flush coalesced ----
    #pragma unroll
    for (int k = 0; k < 13; k++) {
        if (r[k] >= 0) {
            int b = r[k] >> 9;
            int p = offR[b] + atomicAdd(&cntR[b], 1);
            sortB[p] = ((unsigned)c[k] << 9) | ((unsigned)r[k] & 511u);
        }
    }
    __syncthreads();
    for (int i = t; i < m; i += 1024) {
        int lo = 0, hi = NB;                       // offR[lo] <= i < offR[hi]
        while (hi - lo > 1) { int mid = (lo + hi) >> 1; if (offR[mid] <= i) lo = mid; else hi = mid; }
        int g = baseR[lo] + (i - offR[lo]);
        if (g < bcap) RB[(size_t)lo * bcap + g] = sortB[i];
    }
    __syncthreads();

    // ---- col side: reuse the buffer as ushort ----
    unsigned short* sortS = (unsigned short*)sortB;
    #pragma unroll
    for (int k = 0; k < 13; k++) {
        if (r[k] >= 0) {
            int b = c[k] >> 9;
            int q = offC[b] + atomicAdd(&cntC[b], 1);
            sortS[q] = (unsigned short)(c[k] & 511);
        }
    }
    __syncthreads();
    for (int i = t; i < m; i += 1024) {
        int lo = 0, hi = NB;
        while (hi - lo > 1) { int mid = (lo + hi) >> 1; if (offC[mid] <= i) lo = mid; else hi = mid; }
        int g = baseC[lo] + (i - offC[lo]);
        if (g < bcap) CB[(size_t)lo * bcap + g] = sortS[i];
    }
}

// ---------------- Pass B: per-bucket CSR build (512 dst/bucket) + dinv ----------------
__global__ __launch_bounds__(1024) void build_csr_impl(const unsigned int* __restrict__ RB,
                                                       const unsigned short* __restrict__ CB,
                                                       const int* __restrict__ fillR,
                                                       const int* __restrict__ fillC,
                                                       int* __restrict__ rowptr, int* __restrict__ indeg,
                                                       float* __restrict__ dinv, int* __restrict__ csr,
                                                       int n, int NB, int E, int bcap) {
    __shared__ int cnt[512], start[512], bump[512];
    __shared__ int wsum[8];
    __shared__ int s_base;
    int b = blockIdx.x, t = threadIdx.x;
    int node0 = b << 9;

    if (b == 0 && t < 64) csr[E + t] = n;       // pad: unguarded index loads hit zero row

    if (t < 64) {
        int pre = 0;
        for (int j = t; j < b; j += 64) pre += min(fillR[j], bcap);
        #pragma unroll
        for (int off = 32; off; off >>= 1) pre += __shfl_down(pre, off, 64);
        if (t == 0) s_base = pre;
    }
    for (int i = t; i < 512; i += 1024) { cnt[i] = 0; bump[i] = 0; }
    __syncthreads();

    int m = min(fillR[b], bcap);
    const unsigned int* src = RB + (size_t)b * bcap;
    for (int i = t; i < m; i += 1024)
        atomicAdd(&cnt[src[i] & 511u], 1);
    __syncthreads();

    // exclusive scan over 512 counters (threads t<512)
    int my = (t < 512) ? cnt[t] : 0;
    int lane = t & 63, w = t >> 6;              // w in 0..7 for t<512
    int x = my;
    #pragma unroll
    for (int off = 1; off < 64; off <<= 1) {
        int y = __shfl_up(x, off, 64);
        if (lane >= off) x += y;
    }
    if (t < 512 && lane == 63) wsum[w] = x;
    __syncthreads();
    int base = s_base;
    if (t < 512) {
        int wb = 0;
        #pragma unroll
        for (int i = 0; i < 8; i++) if (i < w) wb += wsum[i];
        int excl = wb + x - my;
        start[t] = excl;
        int v = node0 + t;
        if (v < n) { rowptr[v] = base + excl; indeg[v] = my; }
    }
    __syncthreads();
    for (int i = t; i < m; i += 1024) {
        unsigned en = src[i];
        int local = (int)(en & 511u);
        int c = (int)(en >> 9);
        int pos = base + start[local] + atomicAdd(&bump[local], 1);
        if (pos < E) csr[pos] = c;              // hardening: never write OOB
    }
    // col-side histogram -> dinv
    __syncthreads();
    for (int i = t; i < 512; i += 1024) cnt[i] = 0;
    __syncthreads();
    int mc = min(fillC[b], bcap);
    const unsigned short* sc = CB + (size_t)b * bcap;
    for (int i = t; i < mc; i += 1024)
        atomicAdd(&cnt[(int)sc[i] & 511], 1);
    __syncthreads();
    int v = node0 + t;
    if (t < 512 && v < n) dinv[v] = rsqrtf((float)(cnt[t] + 1));
}

// ---------------- dense: Z(bf16, PANEL-MAJOR) = (X @ W) * dinv[:,None] -------
// Block = 64 nodes x 64 outputs. lane = node; wave w owns outputs [16w,16w+16).
// Panel-major storage: panel p (16 features = 8 uints) at p*PSZu + v*8.
// Input: f32 node-major (conv1) or bf16 panel-major (conv2/3).
// Writes rows [v0, min(v0+64, n+1)): row n is the all-zero dummy row.
template <int K, bool BIN>
__global__ __launch_bounds__(256) void gemm_scale(const void* __restrict__ Xv,
                                                  const float* __restrict__ W,
                                                  const float* __restrict__ dinv,
                                                  unsigned* __restrict__ Z, int n, int PSZu) {
    constexpr int KP = K + 4;                      // row stride (floats), 16B-aligned
    __shared__ __align__(16) float xs[64 * KP];
    int v0 = blockIdx.x * 64;
    int t = threadIdx.x;

    if (BIN) {
        const unsigned* Xu = (const unsigned*)Xv;  // bf16 panel-major (K=64: 4 panels)
        constexpr int C8 = K / 8;                  // uint4 chunks per row (8)
        for (int idx = t; idx < 64 * C8; idx += 256) {
            int i = idx / C8, c = idx % C8;        // chunk c: panel c>>1, half c&1
            int v = v0 + i;
            const uint4* src = (const uint4*)(Xu + (size_t)(c >> 1) * PSZu + (size_t)v * 8 + (c & 1) * 4);
            uint4 u = (v < n) ? *src : make_uint4(0, 0, 0, 0);
            float4 f0, f1;
            f0.x = bf16_lo(u.x); f0.y = bf16_hi(u.x); f0.z = bf16_lo(u.y); f0.w = bf16_hi(u.y);
            f1.x = bf16_lo(u.z); f1.y = bf16_hi(u.z); f1.z = bf16_lo(u.w); f1.w = bf16_hi(u.w);
            *(float4*)&xs[i * KP + c * 8] = f0;
            *(float4*)&xs[i * KP + c * 8 + 4] = f1;
        }
    } else {
        const float* X = (const float*)Xv;
        constexpr int C4 = K / 4;
        for (int idx = t; idx < 64 * C4; idx += 256) {
            int i = idx / C4, c = idx % C4;
            int v = v0 + i;
            float4 val = (v < n) ? ((const float4*)(X + (size_t)v * K))[c]
                                 : make_float4(0.f, 0.f, 0.f, 0.f);
            *(float4*)&xs[i * KP + c * 4] = val;
        }
    }
    __syncthreads();

    int lane = t & 63;
    int wave = __builtin_amdgcn_readfirstlane(t >> 6);
    int j0 = wave * 16;
    float acc[16];
    #pragma unroll
    for (int jj = 0; jj < 16; jj++) acc[jj] = 0.f;

    const float* xrow = &xs[lane * KP];
    #pragma unroll 2
    for (int k = 0; k < K; k += 4) {
        float4 xv = *(const float4*)&xrow[k];
        #pragma unroll
        for (int kk = 0; kk < 4; kk++) {
            float xk = (&xv.x)[kk];
            const float* wrow = W + (k + kk) * 64 + j0;   // wave-uniform -> s_load
            #pragma unroll
            for (int jj = 0; jj < 16; jj++)
                acc[jj] = fmaf(xk, wrow[jj], acc[jj]);
        }
    }

    float dv = (v0 + lane < n) ? dinv[v0 + lane] : 0.f;
    __syncthreads();
    // transpose via LDS (reuse xs) with rotate swizzle; store panel-major
    unsigned* zs32 = (unsigned*)xs;                // 64 nodes x 32 uints (2 bf16 each)
    #pragma unroll
    for (int p = 0; p < 8; p++) {
        int pl = (j0 >> 1) + p;                    // logical uint column
        int phys = (pl + lane) & 31;
        zs32[lane * 32 + phys] = pack_bf16(acc[2 * p] * dv, acc[2 * p + 1] * dv);
    }
    __syncthreads();
    for (int idx = t; idx < 2048; idx += 256) {
        int i = idx >> 5, c = idx & 31;            // node i, uint col c; panel c>>3
        int v = v0 + i;
        if (v <= n)                                 // row n = zeros (dummy)
            Z[(size_t)(c >> 3) * PSZu + (size_t)v * 8 + (c & 7)] = zs32[i * 32 + ((c + i) & 31)];
    }
}

// ---------------- sparse aggregate + bias + relu (panel phase) ----------------
// panel = blockIdx.x / NBLK (all panel-0 blocks dispatch first -> each phase's
// 3.2MB panel is L2-resident per XCD; random gathers hit L2).
// One wave per dst node per panel. 8 lanes/edge x 4B (2 features) per lane.
__global__ __launch_bounds__(256) void aggregate(const unsigned* __restrict__ Zp,
                                                 const int* __restrict__ rowptr,
                                                 const int* __restrict__ indeg,
                                                 const int* __restrict__ csr,
                                                 const float* __restrict__ dinv,
                                                 const float* __restrict__ bias,
                                                 unsigned* __restrict__ Xout,
                                                 int n, int NBLK, int PSZu) {
    int wave = threadIdx.x >> 6;
    int lane = threadIdx.x & 63;
    int p  = blockIdx.x / NBLK;              // panel 0..3 (phase)
    int nb = blockIdx.x - p * NBLK;
    int v = nb * 4 + wave;
    if (v >= n) return;
    int vs = __builtin_amdgcn_readfirstlane(v);
    int eg = lane >> 3;                      // edge slot 0..7
    int fl = lane & 7;                       // uint col in panel (features 2fl,2fl+1)
    unsigned un = (unsigned)n;               // dummy zero row index (also clamp)
    const unsigned* Zb = Zp + (size_t)p * PSZu;   // this phase's panel

    int s = rowptr[vs], c = indeg[vs];       // scalar (vs uniform)

    vfloat2 a;
    {
        unsigned sv = (eg == 0) ? Zb[(unsigned)vs * 8u + (unsigned)fl] : 0u;  // self
        a = vfloat2{ bf16_lo(sv), bf16_hi(sv) };
    }

    // edges [0,64): batch-issue live groups (wave-uniform skip of dead ones)
    int live = min((c + 7) >> 3, 8);
    unsigned zz[8];
    #pragma unroll
    for (int g = 0; g < 8; g++) {
        if (g < live) {
            int e = g * 8 + eg;
            unsigned jr = min((unsigned)csr[s + e], un);   // csr +64 pad => safe
            unsigned j = (e < c) ? jr : un;
            zz[g] = Zb[j * 8u + (unsigned)fl];
        }
    }
    #pragma unroll
    for (int g = 0; g < 8; g++) {
        if (g < live) {
            vfloat2 tv = { bf16_lo(zz[g]), bf16_hi(zz[g]) };
            a += tv;
        }
    }

    for (int b = 64; b < c; b += 32) {       // rare: degree > 64
        unsigned j[4];
        #pragma unroll
        for (int g = 0; g < 4; g++) {
            int e = b + g * 8 + eg;
            int er = min(e, c - 1 + 64);     // within padded csr
            unsigned jr = min((unsigned)csr[s + er], un);
            j[g] = (e < c) ? jr : un;
        }
        unsigned zw[4];
        #pragma unroll
        for (int g = 0; g < 4; g++)
            zw[g] = Zb[j[g] * 8u + (unsigned)fl];
        #pragma unroll
        for (int g = 0; g < 4; g++) {
            if (b + g * 8 < c) {
                vfloat2 tv = { bf16_lo(zw[g]), bf16_hi(zw[g]) };
                a += tv;
            }
        }
    }

    // combine the 8 edge slots (lanes fl, fl+8, ..., fl+56)
    #pragma unroll
    for (int st = 8; st <= 32; st <<= 1) {
        vfloat2 o;
        o.x = __shfl_xor(a.x, st, 64);
        o.y = __shfl_xor(a.y, st, 64);
        a += o;
    }

    if (eg == 0) {
        float dv = dinv[vs];
        float2 bb = ((const float2*)bias)[p * 8 + fl];    // features 16p+2fl, +1
        float r0 = fmaxf(fmaf(a.x, dv, bb.x), 0.f);
        float r1 = fmaxf(fmaf(a.y, dv, bb.y), 0.f);
        Xout[(size_t)p * PSZu + (unsigned)vs * 8u + (unsigned)fl] = pack_bf16(r0, r1);
    }
}

// ---------------- fused pool (block per graph, batch sorted) + linear + softmax ----------------
__device__ __forceinline__ int lbound(const int* a, int n, int key) {
    int lo = 0, hi = n;
    while (lo < hi) { int mid = (lo + hi) >> 1; if (a[mid] < key) lo = mid + 1; else hi = mid; }
    return lo;
}

__global__ __launch_bounds__(256) void pool_head(const unsigned* __restrict__ x1,
                                                 const unsigned* __restrict__ x2,
                                                 const unsigned* __restrict__ x3,
                                                 const int* __restrict__ batch,
                                                 const float* __restrict__ Wl,
                                                 const float* __restrict__ bl,
                                                 float* __restrict__ out, int n, int PSZu) {
    __shared__ int sb[2];
    __shared__ float red[4][64];
    __shared__ float ps[64];
    __shared__ float lg[10];
    int g = blockIdx.x, t = threadIdx.x;
    int wave = t >> 6, lane = t & 63;
    if (t < 2) sb[t] = lbound(batch, n, g + t);
    __syncthreads();
    int s0 = sb[0], s1 = sb[1];
    // panel-major reads: 2 nodes per wave per iter, lane reads one uint (2 bf16)
    int half = lane >> 5, col = lane & 31;
    size_t poff = (size_t)(col >> 3) * PSZu + (col & 7);
    float a0 = 0.f, a1 = 0.f;
    for (int v = s0 + wave * 2 + half; v < s1; v += 8) {
        size_t off = poff + (size_t)v * 8;
        unsigned u1 = x1[off], u2 = x2[off], u3 = x3[off];
        a0 += (bf16_lo(u1) + bf16_lo(u2)) + bf16_lo(u3);
        a1 += (bf16_hi(u1) + bf16_hi(u2)) + bf16_hi(u3);
    }
    a0 += __shfl_xor(a0, 32, 64);
    a1 += __shfl_xor(a1, 32, 64);
    if (half == 0) { red[wave][2 * col] = a0; red[wave][2 * col + 1] = a1; }
    __syncthreads();
    if (t < 64) {
        int c = s1 - s0;
        float denom = 3.0f * (float)(c > 1 ? c : 1);
        ps[t] = (red[0][t] + red[1][t] + red[2][t] + red[3][t]) / denom;
    }
    __syncthreads();
    if (t < 10) {
        float a = bl[t];
        #pragma unroll 8
        for (int f = 0; f < 64; f++) a += ps[f] * Wl[f * 10 + t];
        lg[t] = a;
    }
    __syncthreads();
    if (t < 10) {
        float mx = -1e30f;
        for (int j = 0; j < 10; j++) mx = fmaxf(mx, lg[j]);
        float e = expf(lg[t] - mx);
        float ss = 0.f;
        for (int j = 0; j < 10; j++) ss += expf(lg[j] - mx);
        out[g * 10 + t] = e / ss;
    }
}

extern "C" void kernel_launch(void* const* d_in, const int* in_sizes, int n_in,
                              void* d_out, int out_size, void* d_ws, size_t ws_size,
                              hipStream_t stream) {
    const float* feats = (const float*)d_in[0];
    const int*   eidx  = (const int*)d_in[1];
    const int*   batch = (const int*)d_in[2];
    const float* W1 = (const float*)d_in[4];
    const float* b1 = (const float*)d_in[5];
    const float* W2 = (const float*)d_in[6];
    const float* b2 = (const float*)d_in[7];
    const float* W3 = (const float*)d_in[8];
    const float* b3 = (const float*)d_in[9];
    const float* Wl = (const float*)d_in[10];
    const float* bl = (const float*)d_in[11];
    float* out = (float*)d_out;

    int n = in_sizes[0] / 128;
    int E = in_sizes[1] / 2;
    int G = out_size / 10;
    int NB = ((n - 1) >> 9) + 1;                   // 512-node buckets
    int per = E / NB;
    int bcap = ALIGN_UP(per + per / 8 + 512, 64);  // mean + >15 sigma margin
    const int* row = eidx;       // destination
    const int* col = eidx + E;   // source

    // panel geometry: 4 panels x 32B/node (8 uints), stride PSZu uints
    int PSZu = (int)(ALIGN_UP(((size_t)n + 1) * 32, 256) / 4);

    char* ws = (char*)d_ws;
    size_t o = 0;
    size_t o_fill   = o; o += 2 * NBMAX * 4;                         // fillR | fillC (zeroed)
    size_t o_rowptr = o; o += ALIGN_UP((size_t)n * 4, 256);
    size_t o_indeg  = o; o += ALIGN_UP((size_t)n * 4, 256);
    size_t o_dinv   = o; o += ALIGN_UP((size_t)n * 4, 256);
    size_t o_csr    = o; o += ALIGN_UP((size_t)(E + 64) * 4, 256);   // +64 pad entries = n
    size_t o_z      = o; o += (size_t)4 * PSZu * 4;                  // panel-major bf16 Z
    size_t o_union  = o;                                             // RB+CB | x1..x3
    size_t rb_bytes = ALIGN_UP((size_t)NB * bcap * 4, 256);
    size_t xl_bytes = (size_t)4 * PSZu * 4;                          // panel-major x-layers
    (void)ws_size; (void)n_in;

    int*   fillR = (int*)(ws + o_fill);
    int*   fillC = fillR + NBMAX;
    int*   rowptr = (int*)(ws + o_rowptr);
    int*   indeg  = (int*)(ws + o_indeg);
    float* dinv   = (float*)(ws + o_dinv);
    int*   csr    = (int*)(ws + o_csr);
    unsigned* z   = (unsigned*)(ws + o_z);
    unsigned int*   RB = (unsigned int*)(ws + o_union);
    unsigned short* CB = (unsigned short*)(ws + o_union + rb_bytes);
    unsigned* x1 = (unsigned*)(ws + o_union);                        // overlays RB/CB
    unsigned* x2 = (unsigned*)(ws + o_union + xl_bytes);
    unsigned* x3 = (unsigned*)(ws + o_union + 2 * xl_bytes);

    hipMemsetAsync(ws + o_fill, 0, 2 * NBMAX * 4, stream);

    int gridG = n / 64 + 1;      // gemm: 64 nodes per block; always covers dummy row n
    int NBLK  = (n + 3) / 4;     // aggregate: one wave per node per panel
    int gridW = 4 * NBLK;        // 4 panel phases, panel-major dispatch order
    int gridB = (E + CHUNK - 1) / CHUNK;   // bin: chunk <= CHUNK edges/block

    bin_edges_sort<<<gridB, 1024, 0, stream>>>(row, col, E, NB, bcap, fillR, fillC, RB, CB);
    build_csr_impl<<<NB, 1024, 0, stream>>>(RB, CB, fillR, fillC,
                                            rowptr, indeg, dinv, csr, n, NB, E, bcap);

    // conv1 (RB/CB dead after build_csr; x1 overlays them)
    gemm_scale<128, false><<<gridG, 256, 0, stream>>>(feats, W1, dinv, z, n, PSZu);
    aggregate<<<gridW, 256, 0, stream>>>(z, rowptr, indeg, csr, dinv, b1, x1, n, NBLK, PSZu);
    // conv2
    gemm_scale<64, true><<<gridG, 256, 0, stream>>>(x1, W2, dinv, z, n, PSZu);
    aggregate<<<gridW, 256, 0, stream>>>(z, rowptr, indeg, csr, dinv, b2, x2, n, NBLK, PSZu);
    // conv3
    gemm_scale<64, true><<<gridG, 256, 0, stream>>>(x2, W3, dinv, z, n, PSZu);
    aggregate<<<gridW, 256, 0, stream>>>(z, rowptr, indeg, csr, dinv, b3, x3, n, NBLK, PSZu);

    pool_head<<<G, 256, 0, stream>>>(x1, x2, x3, batch, Wl, bl, out, n, PSZu);
}

// Round 9
// 424.469 us; speedup vs baseline: 1.6693x; 1.6693x over previous
//
#include <hip/hip_runtime.h>
#include <hip/hip_bf16.h>

// GCN: 3x GCNConv(relu) -> mean over layers -> global mean pool -> linear -> softmax
// N=100000, E=3200000, F_IN=128, F_HID=64, F_OUT=10, G=1000.
//
// out[dst] = dinv[dst] * ( sum_{e: row[e]=dst} z[col[e]] + z[dst] ) + b,
// z = (x @ W) * dinv[:,None], dinv = rsqrt(deg_col + 1).
//
// R19: R18 (panel-major) proved aggregate is at the L2-miss-fabric floor
// (160MB @ ~3.1TB/s ~= 52us); L2-resident panels cost 4x plumbing (157us).
// Revert to R16 structure (422.8us best) and fix the blind spots:
//  - bin_edges_sort: CHUNK 12500->6250 (grid 256->512 = 2 blocks/CU; was
//    HALF-IDLE at 1 block/CU). Runs stay ~128B so no write-amp.
//  - build_csr: CB histogram into cnt2 CONCURRENT with RB histogram
//    (one fewer LDS zero pass, 2 fewer barriers, overlapped reads).
// aggregate/gemm/pool: R16 exact.

#define ALIGN_UP(x, a) (((x) + (a) - 1) / (a) * (a))
#define NBMAX 256        // max buckets (node id >> 9), supports n <= 131072
#define CHUNK 6250       // max edges per bin block (7 regs/thread, 25KB sort LDS)

typedef float vfloat2 __attribute__((ext_vector_type(2)));

__device__ __forceinline__ float bf16_to_f32(unsigned short u) {
    return __uint_as_float(((unsigned)u) << 16);
}
__device__ __forceinline__ float bf16_lo(unsigned u) {
    return __uint_as_float(u << 16);
}
__device__ __forceinline__ float bf16_hi(unsigned u) {
    return __uint_as_float(u & 0xffff0000u);
}
__device__ __forceinline__ unsigned pack_bf16(float a, float b) {
    union { __hip_bfloat16 h; unsigned short u; } ua, ub;
    ua.h = __float2bfloat16(a); ub.h = __float2bfloat16(b);
    return (unsigned)ua.u | ((unsigned)ub.u << 16);
}

// ---------------- Pass A: LDS radix-partition of edges into 512-node buckets ----
// RB entry = (col<<9)|(row&511); CB entry = ushort col&511.
__global__ __launch_bounds__(1024, 8) void bin_edges_sort(const int* __restrict__ row,
                                                          const int* __restrict__ col,
                                                          int E, int NB, int bcap,
                                                          int* __restrict__ fillR,
                                                          int* __restrict__ fillC,
                                                          unsigned int* __restrict__ RB,
                                                          unsigned short* __restrict__ CB) {
    __shared__ unsigned int sortB[CHUNK + 44];     // 25KB; reused as ushort for C
    __shared__ int cntR[NBMAX], cntC[NBMAX];       // histogram, then scatter cursors
    __shared__ int offR[NBMAX + 1], offC[NBMAX + 1];
    __shared__ int baseR[NBMAX], baseC[NBMAX];
    __shared__ int wsumR[4], wsumC[4];

    int t = threadIdx.x;
    for (int i = t; i < NBMAX; i += 1024) { cntR[i] = 0; cntC[i] = 0; }
    __syncthreads();

    int per = (E + gridDim.x - 1) / gridDim.x;     // <= CHUNK by grid sizing
    int e0 = blockIdx.x * per, e1 = min(E, e0 + per);
    int m = e1 - e0;

    // load chunk ONCE into registers (fully unrolled -> static indexing)
    int r[7], c[7];
    #pragma unroll
    for (int k = 0; k < 7; k++) {
        int e = e0 + t + (k << 10);
        bool ok = e < e1;
        r[k] = ok ? row[e] : -1;
        c[k] = ok ? col[e] : 0;
    }
    // histogram
    #pragma unroll
    for (int k = 0; k < 7; k++) {
        if (r[k] >= 0) {
            atomicAdd(&cntR[r[k] >> 9], 1);
            atomicAdd(&cntC[c[k] >> 9], 1);
        }
    }
    __syncthreads();

    // parallel exclusive scans over 256 counters: waves 0-3 -> R, waves 4-7 -> C
    int idx = t & 255;
    bool isR = t < 256, isC = (t >= 256) && (t < 512);
    int val = isR ? cntR[idx] : (isC ? cntC[idx] : 0);
    int lane = t & 63, w4 = (t >> 6) & 3;
    int x = val;
    #pragma unroll
    for (int off = 1; off < 64; off <<= 1) {
        int y = __shfl_up(x, off, 64);
        if (lane >= off) x += y;
    }
    if (isR && lane == 63) wsumR[w4] = x;
    if (isC && lane == 63) wsumC[w4] = x;
    __syncthreads();
    if (isR) {
        int wb = 0;
        #pragma unroll
        for (int i = 0; i < 4; i++) if (i < w4) wb += wsumR[i];
        offR[idx] = wb + x - val;
        if (idx < NB) baseR[idx] = val ? atomicAdd(&fillR[idx], val) : 0;
    }
    if (isC) {
        int wb = 0;
        #pragma unroll
        for (int i = 0; i < 4; i++) if (i < w4) wb += wsumC[i];
        offC[idx] = wb + x - val;
        if (idx < NB) baseC[idx] = val ? atomicAdd(&fillC[idx], val) : 0;
    }
    if (t == 0) offR[NBMAX] = m;
    if (t == 1) offC[NBMAX] = m;
    __syncthreads();
    for (int i = t; i < NBMAX; i += 1024) { cntR[i] = 0; cntC[i] = 0; }  // -> cursors
    __syncthreads();

    // ---- row side: scatter into LDS-sorted order, flush coalesced ----
    #pragma unroll
    for (int k = 0; k < 7; k++) {
        if (r[k] >= 0) {
            int b = r[k] >> 9;
            int p = offR[b] + atomicAdd(&cntR[b], 1);
            sortB[p] = ((unsigned)c[k] << 9) | ((unsigned)r[k] & 511u);
        }
    }
    __syncthreads();
    for (int i = t; i < m; i += 1024) {
        int lo = 0, hi = NB;                       // offR[lo] <= i < offR[hi]
        while (hi - lo > 1) { int mid = (lo + hi) >> 1; if (offR[mid] <= i) lo = mid; else hi = mid; }
        int g = baseR[lo] + (i - offR[lo]);
        if (g < bcap) RB[(size_t)lo * bcap + g] = sortB[i];
    }
    __syncthreads();

    // ---- col side: reuse the buffer as ushort ----
    unsigned short* sortS = (unsigned short*)sortB;
    #pragma unroll
    for (int k = 0; k < 7; k++) {
        if (r[k] >= 0) {
            int b = c[k] >> 9;
            int q = offC[b] + atomicAdd(&cntC[b], 1);
            sortS[q] = (unsigned short)(c[k] & 511);
        }
    }
    __syncthreads();
    for (int i = t; i < m; i += 1024) {
        int lo = 0, hi = NB;
        while (hi - lo > 1) { int mid = (lo + hi) >> 1; if (offC[mid] <= i) lo = mid; else hi = mid; }
        int g = baseC[lo] + (i - offC[lo]);
        if (g < bcap) CB[(size_t)lo * bcap + g] = sortS[i];
    }
}

// ---------------- Pass B: per-bucket CSR build (512 dst/bucket) + dinv ----------------
// CB histogram runs CONCURRENT with RB histogram (separate cnt2 array).
__global__ __launch_bounds__(1024) void build_csr_impl(const unsigned int* __restrict__ RB,
                                                       const unsigned short* __restrict__ CB,
                                                       const int* __restrict__ fillR,
                                                       const int* __restrict__ fillC,
                                                       int* __restrict__ rowptr, int* __restrict__ indeg,
                                                       float* __restrict__ dinv, int* __restrict__ csr,
                                                       int n, int NB, int E, int bcap) {
    __shared__ int cnt[512], cnt2[512], start[512], bump[512];
    __shared__ int wsum[8];
    __shared__ int s_base;
    int b = blockIdx.x, t = threadIdx.x;
    int node0 = b << 9;

    if (b == 0 && t < 64) csr[E + t] = n;       // pad: unguarded index loads hit zero row

    if (t < 64) {
        int pre = 0;
        for (int j = t; j < b; j += 64) pre += min(fillR[j], bcap);
        #pragma unroll
        for (int off = 32; off; off >>= 1) pre += __shfl_down(pre, off, 64);
        if (t == 0) s_base = pre;
    }
    for (int i = t; i < 512; i += 1024) { cnt[i] = 0; cnt2[i] = 0; bump[i] = 0; }
    __syncthreads();

    int m = min(fillR[b], bcap);
    int mc = min(fillC[b], bcap);
    const unsigned int*   src = RB + (size_t)b * bcap;
    const unsigned short* sc  = CB + (size_t)b * bcap;
    for (int i = t; i < m; i += 1024)
        atomicAdd(&cnt[src[i] & 511u], 1);
    for (int i = t; i < mc; i += 1024)          // overlapped with RB stream
        atomicAdd(&cnt2[(int)sc[i] & 511], 1);
    __syncthreads();

    // exclusive scan over 512 counters (threads t<512)
    int my = (t < 512) ? cnt[t] : 0;
    int lane = t & 63, w = t >> 6;              // w in 0..7 for t<512
    int x = my;
    #pragma unroll
    for (int off = 1; off < 64; off <<= 1) {
        int y = __shfl_up(x, off, 64);
        if (lane >= off) x += y;
    }
    if (t < 512 && lane == 63) wsum[w] = x;
    __syncthreads();
    int base = s_base;
    if (t < 512) {
        int wb = 0;
        #pragma unroll
        for (int i = 0; i < 8; i++) if (i < w) wb += wsum[i];
        int excl = wb + x - my;
        start[t] = excl;
        int v = node0 + t;
        if (v < n) {
            rowptr[v] = base + excl;
            indeg[v] = my;
            dinv[v] = rsqrtf((float)(cnt2[t] + 1));   // cnt2 final since last barrier
        }
    }
    __syncthreads();
    for (int i = t; i < m; i += 1024) {
        unsigned en = src[i];
        int local = (int)(en & 511u);
        int c = (int)(en >> 9);
        int pos = base + start[local] + atomicAdd(&bump[local], 1);
        if (pos < E) csr[pos] = c;              // hardening: never write OOB
    }
}

// ---------------- dense: Z(bf16) = (X @ W) * dinv[:,None] ----------------
// Block = 64 nodes x 64 outputs. lane = node; wave w owns outputs [16w,16w+16).
// W rows are wave-uniform -> scalar s_load. Input f32 (conv1) or bf16 (conv2/3).
// Writes rows [v0, min(v0+64, n+1)): row n is the all-zero dummy row used by
// aggregate's branchless tail.
template <int K, bool BIN>
__global__ __launch_bounds__(256) void gemm_scale(const void* __restrict__ Xv,
                                                  const float* __restrict__ W,
                                                  const float* __restrict__ dinv,
                                                  unsigned* __restrict__ Z, int n) {
    constexpr int KP = K + 4;                      // row stride (floats), 16B-aligned
    __shared__ __align__(16) float xs[64 * KP];
    int v0 = blockIdx.x * 64;
    int t = threadIdx.x;

    if (BIN) {
        const unsigned* Xu = (const unsigned*)Xv;  // bf16-packed rows of K/2 uints
        constexpr int C8 = K / 8;                  // uint4 chunks per row
        for (int idx = t; idx < 64 * C8; idx += 256) {
            int i = idx / C8, c = idx % C8;
            int v = v0 + i;
            uint4 u = (v < n) ? ((const uint4*)(Xu + (size_t)v * (K / 2)))[c]
                              : make_uint4(0, 0, 0, 0);
            float4 f0, f1;
            f0.x = bf16_lo(u.x); f0.y = bf16_hi(u.x); f0.z = bf16_lo(u.y); f0.w = bf16_hi(u.y);
            f1.x = bf16_lo(u.z); f1.y = bf16_hi(u.z); f1.z = bf16_lo(u.w); f1.w = bf16_hi(u.w);
            *(float4*)&xs[i * KP + c * 8] = f0;
            *(float4*)&xs[i * KP + c * 8 + 4] = f1;
        }
    } else {
        const float* X = (const float*)Xv;
        constexpr int C4 = K / 4;
        for (int idx = t; idx < 64 * C4; idx += 256) {
            int i = idx / C4, c = idx % C4;
            int v = v0 + i;
            float4 val = (v < n) ? ((const float4*)(X + (size_t)v * K))[c]
                                 : make_float4(0.f, 0.f, 0.f, 0.f);
            *(float4*)&xs[i * KP + c * 4] = val;
        }
    }
    __syncthreads();

    int lane = t & 63;
    int wave = __builtin_amdgcn_readfirstlane(t >> 6);
    int j0 = wave * 16;
    float acc[16];
    #pragma unroll
    for (int jj = 0; jj < 16; jj++) acc[jj] = 0.f;

    const float* xrow = &xs[lane * KP];
    #pragma unroll 2
    for (int k = 0; k < K; k += 4) {
        float4 xv = *(const float4*)&xrow[k];
        #pragma unroll
        for (int kk = 0; kk < 4; kk++) {
            float xk = (&xv.x)[kk];
            const float* wrow = W + (k + kk) * 64 + j0;   // wave-uniform -> s_load
            #pragma unroll
            for (int jj = 0; jj < 16; jj++)
                acc[jj] = fmaf(xk, wrow[jj], acc[jj]);
        }
    }

    float dv = (v0 + lane < n) ? dinv[v0 + lane] : 0.f;
    __syncthreads();
    // transpose via LDS (reuse xs) with rotate swizzle; store coalesced bf16 rows
    unsigned* zs32 = (unsigned*)xs;                // 64 nodes x 32 uints (2 bf16 each)
    #pragma unroll
    for (int p = 0; p < 8; p++) {
        int pl = (j0 >> 1) + p;                    // logical uint column
        int phys = (pl + lane) & 31;
        zs32[lane * 32 + phys] = pack_bf16(acc[2 * p] * dv, acc[2 * p + 1] * dv);
    }
    __syncthreads();
    for (int idx = t; idx < 2048; idx += 256) {
        int i = idx >> 5, c = idx & 31;
        int v = v0 + i;
        if (v <= n) Z[(size_t)v * 32 + c] = zs32[i * 32 + ((c + i) & 31)];  // row n = zeros
    }
}

// ---------------- sparse aggregate + bias + relu (bf16 gather -> bf16 out) ----------------
// One wave per dst node. 8 lanes per edge (dwordx4 = 8 features), one wave
// VMEM instr = 8 edges = 8 x 128B lines. Edge indices loaded directly per group
// (8 lanes share one dword; csr padded with n). Gather addresses are 32-bit
// voffsets off a uniform base (saddr form). At the L2-miss fabric floor
// (~160MB @ ~3.1TB/s) -- measured best structure (R16).
__device__ __forceinline__ void acc8pk(vfloat2 a[4], uint4 z) {
    vfloat2 t0 = { bf16_lo(z.x), bf16_hi(z.x) };
    vfloat2 t1 = { bf16_lo(z.y), bf16_hi(z.y) };
    vfloat2 t2 = { bf16_lo(z.z), bf16_hi(z.z) };
    vfloat2 t3 = { bf16_lo(z.w), bf16_hi(z.w) };
    a[0] += t0; a[1] += t1; a[2] += t2; a[3] += t3;
}

__global__ __launch_bounds__(256) void aggregate(const uint4* __restrict__ Z4,
                                                 const int* __restrict__ rowptr,
                                                 const int* __restrict__ indeg,
                                                 const int* __restrict__ csr,
                                                 const float* __restrict__ dinv,
                                                 const float* __restrict__ bias,
                                                 uint4* __restrict__ Xout, int n) {
    int wave = threadIdx.x >> 6;
    int lane = threadIdx.x & 63;
    int v = blockIdx.x * 4 + wave;
    if (v >= n) return;
    int vs = __builtin_amdgcn_readfirstlane(v);
    int eg = lane >> 3;                      // edge slot 0..7
    int fl = lane & 7;                       // feature octet (features 8fl..8fl+7)
    unsigned un = (unsigned)n;               // dummy zero row index (also clamp)
    const char* Zb = (const char*)Z4;
    unsigned fo = (unsigned)(fl << 4);       // feature byte offset within row

    int s = rowptr[vs], c = indeg[vs];       // scalar (vs uniform)

    vfloat2 a[4];
    {
        uint4 sv = make_uint4(0u, 0u, 0u, 0u);
        if (eg == 0) sv = *(const uint4*)(Zb + (((unsigned)vs << 7) + fo));  // self-loop
        a[0] = vfloat2{ bf16_lo(sv.x), bf16_hi(sv.x) };
        a[1] = vfloat2{ bf16_lo(sv.y), bf16_hi(sv.y) };
        a[2] = vfloat2{ bf16_lo(sv.z), bf16_hi(sv.z) };
        a[3] = vfloat2{ bf16_lo(sv.w), bf16_hi(sv.w) };
    }

    // chunk [0,32): 4 index loads (unguarded, pad-safe) -> 4 gathers in flight,
    // acc skipped per dead group by wave-uniform branch (c scalar).
    {
        unsigned j[4];
        #pragma unroll
        for (int g = 0; g < 4; g++) {
            int e = g * 8 + eg;
            unsigned jr = min((unsigned)csr[s + e], un);
            j[g] = (e < c) ? jr : un;
        }
        uint4 zz[4];
        #pragma unroll
        for (int g = 0; g < 4; g++)
            zz[g] = *(const uint4*)(Zb + ((j[g] << 7) + fo));
        #pragma unroll
        for (int g = 0; g < 4; g++)
            if (g * 8 < c) acc8pk(a, zz[g]);
    }
    if (c > 32) {   // chunk [32,64): skipped entirely for 54% of nodes
        unsigned j[4];
        #pragma unroll
        for (int g = 0; g < 4; g++) {
            int e = 32 + g * 8 + eg;
            unsigned jr = min((unsigned)csr[s + e], un);
            j[g] = (e < c) ? jr : un;
        }
        uint4 zz[4];
        #pragma unroll
        for (int g = 0; g < 4; g++)
            zz[g] = *(const uint4*)(Zb + ((j[g] << 7) + fo));
        #pragma unroll
        for (int g = 0; g < 4; g++)
            if (32 + g * 8 < c) acc8pk(a, zz[g]);
    }
    for (int b = 64; b < c; b += 32) {   // rare: degree > 64 (csr pad keeps reads safe)
        unsigned j[4];
        #pragma unroll
        for (int g = 0; g < 4; g++) {
            int e = b + g * 8 + eg;
            int er = min(e, c - 1 + 64);             // within padded csr
            unsigned jr = min((unsigned)csr[s + er], un);
            j[g] = (e < c) ? jr : un;
        }
        uint4 zw[4];
        #pragma unroll
        for (int g = 0; g < 4; g++)
            zw[g] = *(const uint4*)(Zb + ((j[g] << 7) + fo));
        #pragma unroll
        for (int g = 0; g < 4; g++)
            if (b + g * 8 < c) acc8pk(a, zw[g]);
    }

    // combine the 8 edge slots (lanes fl, fl+8, ..., fl+56)
    #pragma unroll
    for (int p = 0; p < 4; p++) {
        vfloat2 o;
        o.x = __shfl_xor(a[p].x, 8, 64);  o.y = __shfl_xor(a[p].y, 8, 64);
        a[p] += o;
        o.x = __shfl_xor(a[p].x, 16, 64); o.y = __shfl_xor(a[p].y, 16, 64);
        a[p] += o;
        o.x = __shfl_xor(a[p].x, 32, 64); o.y = __shfl_xor(a[p].y, 32, 64);
        a[p] += o;
    }

    if (eg == 0) {
        float dv = dinv[vs];
        float4 b0 = ((const float4*)bias)[2 * fl];
        float4 b1 = ((const float4*)bias)[2 * fl + 1];
        float r0 = fmaxf(fmaf(a[0].x, dv, b0.x), 0.f);
        float r1 = fmaxf(fmaf(a[0].y, dv, b0.y), 0.f);
        float r2 = fmaxf(fmaf(a[1].x, dv, b0.z), 0.f);
        float r3 = fmaxf(fmaf(a[1].y, dv, b0.w), 0.f);
        float r4 = fmaxf(fmaf(a[2].x, dv, b1.x), 0.f);
        float r5 = fmaxf(fmaf(a[2].y, dv, b1.y), 0.f);
        float r6 = fmaxf(fmaf(a[3].x, dv, b1.z), 0.f);
        float r7 = fmaxf(fmaf(a[3].y, dv, b1.w), 0.f);
        Xout[(size_t)vs * 8 + fl] = make_uint4(pack_bf16(r0, r1), pack_bf16(r2, r3),
                                               pack_bf16(r4, r5), pack_bf16(r6, r7));
    }
}

// ---------------- fused pool (block per graph, batch sorted) + linear + softmax ----------------
__device__ __forceinline__ int lbound(const int* a, int n, int key) {
    int lo = 0, hi = n;
    while (lo < hi) { int mid = (lo + hi) >> 1; if (a[mid] < key) lo = mid + 1; else hi = mid; }
    return lo;
}

__global__ __launch_bounds__(256) void pool_head(const unsigned* __restrict__ x1,
                                                 const unsigned* __restrict__ x2,
                                                 const unsigned* __restrict__ x3,
                                                 const int* __restrict__ batch,
                                                 const float* __restrict__ Wl,
                                                 const float* __restrict__ bl,
                                                 float* __restrict__ out, int n) {
    __shared__ int sb[2];
    __shared__ float red[4][64];
    __shared__ float ps[64];
    __shared__ float lg[10];
    int g = blockIdx.x, t = threadIdx.x;
    int wave = t >> 6, lane = t & 63;
    if (t < 2) sb[t] = lbound(batch, n, g + t);
    __syncthreads();
    int s0 = sb[0], s1 = sb[1];
    // packed loads: 2 nodes per wave per iter, each lane reads one uint (2 bf16)
    int half = lane >> 5, col = lane & 31;
    float a0 = 0.f, a1 = 0.f;
    for (int v = s0 + wave * 2 + half; v < s1; v += 8) {
        size_t off = (size_t)v * 32 + col;
        unsigned u1 = x1[off], u2 = x2[off], u3 = x3[off];
        a0 += (bf16_lo(u1) + bf16_lo(u2)) + bf16_lo(u3);
        a1 += (bf16_hi(u1) + bf16_hi(u2)) + bf16_hi(u3);
    }
    a0 += __shfl_xor(a0, 32, 64);
    a1 += __shfl_xor(a1, 32, 64);
    if (half == 0) { red[wave][2 * col] = a0; red[wave][2 * col + 1] = a1; }
    __syncthreads();
    if (t < 64) {
        int c = s1 - s0;
        float denom = 3.0f * (float)(c > 1 ? c : 1);
        ps[t] = (red[0][t] + red[1][t] + red[2][t] + red[3][t]) / denom;
    }
    __syncthreads();
    if (t < 10) {
        float a = bl[t];
        #pragma unroll 8
        for (int f = 0; f < 64; f++) a += ps[f] * Wl[f * 10 + t];
        lg[t] = a;
    }
    __syncthreads();
    if (t < 10) {
        float mx = -1e30f;
        for (int j = 0; j < 10; j++) mx = fmaxf(mx, lg[j]);
        float e = expf(lg[t] - mx);
        float ss = 0.f;
        for (int j = 0; j < 10; j++) ss += expf(lg[j] - mx);
        out[g * 10 + t] = e / ss;
    }
}

extern "C" void kernel_launch(void* const* d_in, const int* in_sizes, int n_in,
                              void* d_out, int out_size, void* d_ws, size_t ws_size,
                              hipStream_t stream) {
    const float* feats = (const float*)d_in[0];
    const int*   eidx  = (const int*)d_in[1];
    const int*   batch = (const int*)d_in[2];
    const float* W1 = (const float*)d_in[4];
    const float* b1 = (const float*)d_in[5];
    const float* W2 = (const float*)d_in[6];
    const float* b2 = (const float*)d_in[7];
    const float* W3 = (const float*)d_in[8];
    const float* b3 = (const float*)d_in[9];
    const float* Wl = (const float*)d_in[10];
    const float* bl = (const float*)d_in[11];
    float* out = (float*)d_out;

    int n = in_sizes[0] / 128;
    int E = in_sizes[1] / 2;
    int G = out_size / 10;
    int NB = ((n - 1) >> 9) + 1;                   // 512-node buckets
    int per = E / NB;
    int bcap = ALIGN_UP(per + per / 8 + 512, 64);  // mean + >15 sigma margin
    const int* row = eidx;       // destination
    const int* col = eidx + E;   // source

    char* ws = (char*)d_ws;
    size_t o = 0;
    size_t o_fill   = o; o += 2 * NBMAX * 4;                         // fillR | fillC (zeroed)
    size_t o_rowptr = o; o += ALIGN_UP((size_t)n * 4, 256);
    size_t o_indeg  = o; o += ALIGN_UP((size_t)n * 4, 256);
    size_t o_dinv   = o; o += ALIGN_UP((size_t)n * 4, 256);
    size_t o_csr    = o; o += ALIGN_UP((size_t)(E + 64) * 4, 256);   // +64 pad entries = n
    size_t o_z      = o; o += ALIGN_UP(((size_t)n + 1) * 64 * 2, 256); // bf16 Z (+dummy row n)
    size_t o_union  = o;                                             // RB+CB | x1..x3
    size_t rb_bytes = ALIGN_UP((size_t)NB * bcap * 4, 256);
    size_t xl_bytes = ALIGN_UP((size_t)n * 64 * 2, 256);             // bf16 x-layers
    (void)ws_size; (void)n_in;

    int*   fillR = (int*)(ws + o_fill);
    int*   fillC = fillR + NBMAX;
    int*   rowptr = (int*)(ws + o_rowptr);
    int*   indeg  = (int*)(ws + o_indeg);
    float* dinv   = (float*)(ws + o_dinv);
    int*   csr    = (int*)(ws + o_csr);
    unsigned* z   = (unsigned*)(ws + o_z);
    unsigned int*   RB = (unsigned int*)(ws + o_union);
    unsigned short* CB = (unsigned short*)(ws + o_union + rb_bytes);
    unsigned* x1 = (unsigned*)(ws + o_union);                        // overlays RB/CB
    unsigned* x2 = (unsigned*)(ws + o_union + xl_bytes);
    unsigned* x3 = (unsigned*)(ws + o_union + 2 * xl_bytes);

    hipMemsetAsync(ws + o_fill, 0, 2 * NBMAX * 4, stream);

    int gridG = n / 64 + 1;      // gemm: 64 nodes per block; always covers dummy row n
    int gridW = (n + 3) / 4;     // aggregate: one wave per node
    int gridB = (E + CHUNK - 1) / CHUNK;   // bin: 512 blocks (2/CU)

    bin_edges_sort<<<gridB, 1024, 0, stream>>>(row, col, E, NB, bcap, fillR, fillC, RB, CB);
    build_csr_impl<<<NB, 1024, 0, stream>>>(RB, CB, fillR, fillC,
                                            rowptr, indeg, dinv, csr, n, NB, E, bcap);

    // conv1 (RB/CB dead after build_csr; x1 overlays them)
    gemm_scale<128, false><<<gridG, 256, 0, stream>>>(feats, W1, dinv, z, n);
    aggregate<<<gridW, 256, 0, stream>>>((const uint4*)z, rowptr, indeg, csr, dinv, b1, (uint4*)x1, n);
    // conv2
    gemm_scale<64, true><<<gridG, 256, 0, stream>>>(x1, W2, dinv, z, n);
    aggregate<<<gridW, 256, 0, stream>>>((const uint4*)z, rowptr, indeg, csr, dinv, b2, (uint4*)x2, n);
    // conv3
    gemm_scale<64, true><<<gridG, 256, 0, stream>>>(x2, W3, dinv, z, n);
    aggregate<<<gridW, 256, 0, stream>>>((const uint4*)z, rowptr, indeg, csr, dinv, b3, (uint4*)x3, n);

    pool_head<<<G, 256, 0, stream>>>((const unsigned*)x1, (const unsigned*)x2,
                                     (const unsigned*)x3, batch, Wl, bl, out, n);
}

// Round 10
// 386.780 us; speedup vs baseline: 1.8320x; 1.0974x over previous
//
#include <hip/hip_runtime.h>
#include <hip/hip_bf16.h>

// GCN: 3x GCNConv(relu) -> mean over layers -> global mean pool -> linear -> softmax
// N=100000, E=3200000, F_IN=128, F_HID=64, F_OUT=10, G=1000.
//
// out[dst] = dinv[dst] * ( sum_{e: row[e]=dst} z[col[e]] + z[dst] ) + b,
// z = (x @ W) * dinv[:,None], dinv = rsqrt(deg_col + 1).
//
// R20: aggregate is at its L2-miss-fabric floor (~55us, R17/R18 proved).
// R19's bin/build tweaks were neutral -> remaining ~260us is gemm-dominated.
// This round: gemms moved to MFMA (mfma_f32_16x16x32_bf16).
//  - A (X) and B (W) staged to LDS as bf16 with ^((row&7)<<4) XOR swizzle ->
//    ds_read_b128 fragment loads ~2-way conflict-free.
//  - fragments: A row=lane&15, k=8*(lane>>4)+i; B col=lane&15 same k;
//    D col=lane&15, row=4*(lane>>4)+reg (m89-verified layouts).
//  - wave w owns 16-node strip; 4 n-tiles x K/32 k-steps; f32 acc; *dinv in
//    epilogue; LDS f32 transpose (aliases dead staging) -> packed bf16 rows.
//  - conv1 casts X,W to bf16 (error ~ existing bf16-storage error; R12
//    passed at 2^-10). conv2/3 inputs already bf16: no new error.
// bin_edges_sort / build_csr / aggregate / pool_head unchanged from R19.

#define ALIGN_UP(x, a) (((x) + (a) - 1) / (a) * (a))
#define NBMAX 256        // max buckets (node id >> 9), supports n <= 131072
#define CHUNK 6250       // max edges per bin block (7 regs/thread, 25KB sort LDS)

typedef float vfloat2 __attribute__((ext_vector_type(2)));
typedef __bf16 bf16v8 __attribute__((ext_vector_type(8)));
typedef float f32x4 __attribute__((ext_vector_type(4)));

__device__ __forceinline__ float bf16_to_f32(unsigned short u) {
    return __uint_as_float(((unsigned)u) << 16);
}
__device__ __forceinline__ float bf16_lo(unsigned u) {
    return __uint_as_float(u << 16);
}
__device__ __forceinline__ float bf16_hi(unsigned u) {
    return __uint_as_float(u & 0xffff0000u);
}
__device__ __forceinline__ unsigned pack_bf16(float a, float b) {
    union { __hip_bfloat16 h; unsigned short u; } ua, ub;
    ua.h = __float2bfloat16(a); ub.h = __float2bfloat16(b);
    return (unsigned)ua.u | ((unsigned)ub.u << 16);
}
__device__ __forceinline__ unsigned short f2bf(float a) {
    union { __hip_bfloat16 h; unsigned short u; } ua;
    ua.h = __float2bfloat16(a);
    return ua.u;
}

// ---------------- Pass A: LDS radix-partition of edges into 512-node buckets ----
// RB entry = (col<<9)|(row&511); CB entry = ushort col&511.
__global__ __launch_bounds__(1024, 8) void bin_edges_sort(const int* __restrict__ row,
                                                          const int* __restrict__ col,
                                                          int E, int NB, int bcap,
                                                          int* __restrict__ fillR,
                                                          int* __restrict__ fillC,
                                                          unsigned int* __restrict__ RB,
                                                          unsigned short* __restrict__ CB) {
    __shared__ unsigned int sortB[CHUNK + 44];     // 25KB; reused as ushort for C
    __shared__ int cntR[NBMAX], cntC[NBMAX];       // histogram, then scatter cursors
    __shared__ int offR[NBMAX + 1], offC[NBMAX + 1];
    __shared__ int baseR[NBMAX], baseC[NBMAX];
    __shared__ int wsumR[4], wsumC[4];

    int t = threadIdx.x;
    for (int i = t; i < NBMAX; i += 1024) { cntR[i] = 0; cntC[i] = 0; }
    __syncthreads();

    int per = (E + gridDim.x - 1) / gridDim.x;     // <= CHUNK by grid sizing
    int e0 = blockIdx.x * per, e1 = min(E, e0 + per);
    int m = e1 - e0;

    // load chunk ONCE into registers (fully unrolled -> static indexing)
    int r[7], c[7];
    #pragma unroll
    for (int k = 0; k < 7; k++) {
        int e = e0 + t + (k << 10);
        bool ok = e < e1;
        r[k] = ok ? row[e] : -1;
        c[k] = ok ? col[e] : 0;
    }
    // histogram
    #pragma unroll
    for (int k = 0; k < 7; k++) {
        if (r[k] >= 0) {
            atomicAdd(&cntR[r[k] >> 9], 1);
            atomicAdd(&cntC[c[k] >> 9], 1);
        }
    }
    __syncthreads();

    // parallel exclusive scans over 256 counters: waves 0-3 -> R, waves 4-7 -> C
    int idx = t & 255;
    bool isR = t < 256, isC = (t >= 256) && (t < 512);
    int val = isR ? cntR[idx] : (isC ? cntC[idx] : 0);
    int lane = t & 63, w4 = (t >> 6) & 3;
    int x = val;
    #pragma unroll
    for (int off = 1; off < 64; off <<= 1) {
        int y = __shfl_up(x, off, 64);
        if (lane >= off) x += y;
    }
    if (isR && lane == 63) wsumR[w4] = x;
    if (isC && lane == 63) wsumC[w4] = x;
    __syncthreads();
    if (isR) {
        int wb = 0;
        #pragma unroll
        for (int i = 0; i < 4; i++) if (i < w4) wb += wsumR[i];
        offR[idx] = wb + x - val;
        if (idx < NB) baseR[idx] = val ? atomicAdd(&fillR[idx], val) : 0;
    }
    if (isC) {
        int wb = 0;
        #pragma unroll
        for (int i = 0; i < 4; i++) if (i < w4) wb += wsumC[i];
        offC[idx] = wb + x - val;
        if (idx < NB) baseC[idx] = val ? atomicAdd(&fillC[idx], val) : 0;
    }
    if (t == 0) offR[NBMAX] = m;
    if (t == 1) offC[NBMAX] = m;
    __syncthreads();
    for (int i = t; i < NBMAX; i += 1024) { cntR[i] = 0; cntC[i] = 0; }  // -> cursors
    __syncthreads();

    // ---- row side: scatter into LDS-sorted order, flush coalesced ----
    #pragma unroll
    for (int k = 0; k < 7; k++) {
        if (r[k] >= 0) {
            int b = r[k] >> 9;
            int p = offR[b] + atomicAdd(&cntR[b], 1);
            sortB[p] = ((unsigned)c[k] << 9) | ((unsigned)r[k] & 511u);
        }
    }
    __syncthreads();
    for (int i = t; i < m; i += 1024) {
        int lo = 0, hi = NB;                       // offR[lo] <= i < offR[hi]
        while (hi - lo > 1) { int mid = (lo + hi) >> 1; if (offR[mid] <= i) lo = mid; else hi = mid; }
        int g = baseR[lo] + (i - offR[lo]);
        if (g < bcap) RB[(size_t)lo * bcap + g] = sortB[i];
    }
    __syncthreads();

    // ---- col side: reuse the buffer as ushort ----
    unsigned short* sortS = (unsigned short*)sortB;
    #pragma unroll
    for (int k = 0; k < 7; k++) {
        if (r[k] >= 0) {
            int b = c[k] >> 9;
            int q = offC[b] + atomicAdd(&cntC[b], 1);
            sortS[q] = (unsigned short)(c[k] & 511);
        }
    }
    __syncthreads();
    for (int i = t; i < m; i += 1024) {
        int lo = 0, hi = NB;
        while (hi - lo > 1) { int mid = (lo + hi) >> 1; if (offC[mid] <= i) lo = mid; else hi = mid; }
        int g = baseC[lo] + (i - offC[lo]);
        if (g < bcap) CB[(size_t)lo * bcap + g] = sortS[i];
    }
}

// ---------------- Pass B: per-bucket CSR build (512 dst/bucket) + dinv ----------------
// CB histogram runs CONCURRENT with RB histogram (separate cnt2 array).
__global__ __launch_bounds__(1024) void build_csr_impl(const unsigned int* __restrict__ RB,
                                                       const unsigned short* __restrict__ CB,
                                                       const int* __restrict__ fillR,
                                                       const int* __restrict__ fillC,
                                                       int* __restrict__ rowptr, int* __restrict__ indeg,
                                                       float* __restrict__ dinv, int* __restrict__ csr,
                                                       int n, int NB, int E, int bcap) {
    __shared__ int cnt[512], cnt2[512], start[512], bump[512];
    __shared__ int wsum[8];
    __shared__ int s_base;
    int b = blockIdx.x, t = threadIdx.x;
    int node0 = b << 9;

    if (b == 0 && t < 64) csr[E + t] = n;       // pad: unguarded index loads hit zero row

    if (t < 64) {
        int pre = 0;
        for (int j = t; j < b; j += 64) pre += min(fillR[j], bcap);
        #pragma unroll
        for (int off = 32; off; off >>= 1) pre += __shfl_down(pre, off, 64);
        if (t == 0) s_base = pre;
    }
    for (int i = t; i < 512; i += 1024) { cnt[i] = 0; cnt2[i] = 0; bump[i] = 0; }
    __syncthreads();

    int m = min(fillR[b], bcap);
    int mc = min(fillC[b], bcap);
    const unsigned int*   src = RB + (size_t)b * bcap;
    const unsigned short* sc  = CB + (size_t)b * bcap;
    for (int i = t; i < m; i += 1024)
        atomicAdd(&cnt[src[i] & 511u], 1);
    for (int i = t; i < mc; i += 1024)          // overlapped with RB stream
        atomicAdd(&cnt2[(int)sc[i] & 511], 1);
    __syncthreads();

    // exclusive scan over 512 counters (threads t<512)
    int my = (t < 512) ? cnt[t] : 0;
    int lane = t & 63, w = t >> 6;              // w in 0..7 for t<512
    int x = my;
    #pragma unroll
    for (int off = 1; off < 64; off <<= 1) {
        int y = __shfl_up(x, off, 64);
        if (lane >= off) x += y;
    }
    if (t < 512 && lane == 63) wsum[w] = x;
    __syncthreads();
    int base = s_base;
    if (t < 512) {
        int wb = 0;
        #pragma unroll
        for (int i = 0; i < 8; i++) if (i < w) wb += wsum[i];
        int excl = wb + x - my;
        start[t] = excl;
        int v = node0 + t;
        if (v < n) {
            rowptr[v] = base + excl;
            indeg[v] = my;
            dinv[v] = rsqrtf((float)(cnt2[t] + 1));   // cnt2 final since last barrier
        }
    }
    __syncthreads();
    for (int i = t; i < m; i += 1024) {
        unsigned en = src[i];
        int local = (int)(en & 511u);
        int c = (int)(en >> 9);
        int pos = base + start[local] + atomicAdd(&bump[local], 1);
        if (pos < E) csr[pos] = c;              // hardening: never write OOB
    }
}

// ---------------- dense MFMA: Z(bf16) = (X @ W) * dinv[:,None] ----------------
// Block = 64 nodes x 64 outputs, 4 waves. Wave w owns node rows [16w,16w+16).
// X and W staged to LDS as bf16, XOR-swizzled (^((row&7)<<4)) for conflict-free
// ds_read_b128 fragment loads. Fragments (HW-verified layouts):
//   A: row = lane&15, k = ks*32 + 8*(lane>>4) + i
//   B: col = lane&15, same k               (wt stored transposed: [n][k])
//   D: col = lane&15, row = 4*(lane>>4) + reg
// Epilogue: *dinv, f32 LDS transpose (aliases dead staging), pack bf16 rows.
template <int K, bool BIN>
__global__ __launch_bounds__(256) void gemm_mfma(const void* __restrict__ Xv,
                                                 const float* __restrict__ W,
                                                 const float* __restrict__ dinv,
                                                 unsigned* __restrict__ Z, int n) {
    constexpr int RS = 2 * K;                          // bf16 row stride in bytes
    constexpr int XS = 64 * RS;                        // xs region bytes
    constexpr int SMEM = (2 * XS > 64 * 68 * 4) ? 2 * XS : 64 * 68 * 4;
    __shared__ __align__(16) char sm[SMEM];
    int v0 = blockIdx.x * 64;
    int t = threadIdx.x;

    // ---- stage X (bf16, swizzled) ----
    constexpr int C8 = K / 8;                          // 16B chunks per row
    if (BIN) {
        const unsigned* Xu = (const unsigned*)Xv;      // bf16 rows of K/2 uints
        for (int idx = t; idx < 64 * C8; idx += 256) {
            int i = idx / C8, cp = idx % C8;
            int v = v0 + i;
            uint4 u = (v < n) ? ((const uint4*)(Xu + (size_t)v * (K / 2)))[cp]
                              : make_uint4(0, 0, 0, 0);
            int d = (i * RS + cp * 16) ^ ((i & 7) << 4);
            *(uint4*)(sm + d) = u;
        }
    } else {
        const float* X = (const float*)Xv;
        for (int idx = t; idx < 64 * C8; idx += 256) {
            int i = idx / C8, cp = idx % C8;
            int v = v0 + i;
            float4 f0 = make_float4(0.f, 0.f, 0.f, 0.f), f1 = f0;
            if (v < n) {
                f0 = ((const float4*)(X + (size_t)v * K))[cp * 2];
                f1 = ((const float4*)(X + (size_t)v * K))[cp * 2 + 1];
            }
            uint4 u;
            u.x = pack_bf16(f0.x, f0.y); u.y = pack_bf16(f0.z, f0.w);
            u.z = pack_bf16(f1.x, f1.y); u.w = pack_bf16(f1.z, f1.w);
            int d = (i * RS + cp * 16) ^ ((i & 7) << 4);
            *(uint4*)(sm + d) = u;
        }
    }
    // ---- stage W transposed (wt[n][k], bf16, swizzled) ----
    {
        int nn = t & 63, k0 = t >> 6;                  // k0 in 0..3
        for (int k = k0; k < K; k += 4) {
            unsigned short wb = f2bf(W[k * 64 + nn]);
            int d = (XS + nn * RS + k * 2) ^ ((nn & 7) << 4);
            *(unsigned short*)(sm + d) = wb;
        }
    }
    __syncthreads();

    int lane = t & 63;
    int wave = __builtin_amdgcn_readfirstlane(t >> 6);
    int m0 = wave * 16;
    int lm = lane & 15, kg = lane >> 4;

    f32x4 acc[4];
    #pragma unroll
    for (int tl = 0; tl < 4; tl++) acc[tl] = f32x4{0.f, 0.f, 0.f, 0.f};

    #pragma unroll
    for (int ks = 0; ks < K / 32; ks++) {
        int ao = ((m0 + lm) * RS + ks * 64 + kg * 16) ^ ((lm & 7) << 4);
        bf16v8 a = *(const bf16v8*)(sm + ao);
        #pragma unroll
        for (int tl = 0; tl < 4; tl++) {
            int bo = (XS + (16 * tl + lm) * RS + ks * 64 + kg * 16) ^ ((lm & 7) << 4);
            bf16v8 b = *(const bf16v8*)(sm + bo);
            acc[tl] = __builtin_amdgcn_mfma_f32_16x16x32_bf16(a, b, acc[tl], 0, 0, 0);
        }
    }

    // per-reg dinv (node rows m0 + 4*kg + i)
    float dvr[4];
    #pragma unroll
    for (int i = 0; i < 4; i++) {
        int vi = v0 + m0 + 4 * kg + i;
        dvr[i] = (vi < n) ? dinv[vi] : 0.f;
    }

    __syncthreads();                                   // staging dead; reuse as f32 out
    float* outf = (float*)sm;
    #pragma unroll
    for (int tl = 0; tl < 4; tl++)
        #pragma unroll
        for (int i = 0; i < 4; i++)
            outf[(m0 + 4 * kg + i) * 68 + 16 * tl + lm] = acc[tl][i] * dvr[i];
    __syncthreads();

    // pack coalesced bf16 rows: Z[v][c] = (f[2c], f[2c+1])
    for (int idx = t; idx < 2048; idx += 256) {
        int i = idx >> 5, c = idx & 31;
        int v = v0 + i;
        if (v <= n)                                    // row n = zeros (dummy)
            Z[(size_t)v * 32 + c] = pack_bf16(outf[i * 68 + 2 * c], outf[i * 68 + 2 * c + 1]);
    }
}

// ---------------- sparse aggregate + bias + relu (bf16 gather -> bf16 out) ----------------
// One wave per dst node. 8 lanes per edge (dwordx4 = 8 features), one wave
// VMEM instr = 8 edges = 8 x 128B lines. At the L2-miss fabric floor
// (~160MB @ ~3.2TB/s) -- measured best structure (R16/R19).
__device__ __forceinline__ void acc8pk(vfloat2 a[4], uint4 z) {
    vfloat2 t0 = { bf16_lo(z.x), bf16_hi(z.x) };
    vfloat2 t1 = { bf16_lo(z.y), bf16_hi(z.y) };
    vfloat2 t2 = { bf16_lo(z.z), bf16_hi(z.z) };
    vfloat2 t3 = { bf16_lo(z.w), bf16_hi(z.w) };
    a[0] += t0; a[1] += t1; a[2] += t2; a[3] += t3;
}

__global__ __launch_bounds__(256) void aggregate(const uint4* __restrict__ Z4,
                                                 const int* __restrict__ rowptr,
                                                 const int* __restrict__ indeg,
                                                 const int* __restrict__ csr,
                                                 const float* __restrict__ dinv,
                                                 const float* __restrict__ bias,
                                                 uint4* __restrict__ Xout, int n) {
    int wave = threadIdx.x >> 6;
    int lane = threadIdx.x & 63;
    int v = blockIdx.x * 4 + wave;
    if (v >= n) return;
    int vs = __builtin_amdgcn_readfirstlane(v);
    int eg = lane >> 3;                      // edge slot 0..7
    int fl = lane & 7;                       // feature octet (features 8fl..8fl+7)
    unsigned un = (unsigned)n;               // dummy zero row index (also clamp)
    const char* Zb = (const char*)Z4;
    unsigned fo = (unsigned)(fl << 4);       // feature byte offset within row

    int s = rowptr[vs], c = indeg[vs];       // scalar (vs uniform)

    vfloat2 a[4];
    {
        uint4 sv = make_uint4(0u, 0u, 0u, 0u);
        if (eg == 0) sv = *(const uint4*)(Zb + (((unsigned)vs << 7) + fo));  // self-loop
        a[0] = vfloat2{ bf16_lo(sv.x), bf16_hi(sv.x) };
        a[1] = vfloat2{ bf16_lo(sv.y), bf16_hi(sv.y) };
        a[2] = vfloat2{ bf16_lo(sv.z), bf16_hi(sv.z) };
        a[3] = vfloat2{ bf16_lo(sv.w), bf16_hi(sv.w) };
    }

    // chunk [0,32): 4 index loads (unguarded, pad-safe) -> 4 gathers in flight,
    // acc skipped per dead group by wave-uniform branch (c scalar).
    {
        unsigned j[4];
        #pragma unroll
        for (int g = 0; g < 4; g++) {
            int e = g * 8 + eg;
            unsigned jr = min((unsigned)csr[s + e], un);
            j[g] = (e < c) ? jr : un;
        }
        uint4 zz[4];
        #pragma unroll
        for (int g = 0; g < 4; g++)
            zz[g] = *(const uint4*)(Zb + ((j[g] << 7) + fo));
        #pragma unroll
        for (int g = 0; g < 4; g++)
            if (g * 8 < c) acc8pk(a, zz[g]);
    }
    if (c > 32) {   // chunk [32,64): skipped entirely for 54% of nodes
        unsigned j[4];
        #pragma unroll
        for (int g = 0; g < 4; g++) {
            int e = 32 + g * 8 + eg;
            unsigned jr = min((unsigned)csr[s + e], un);
            j[g] = (e < c) ? jr : un;
        }
        uint4 zz[4];
        #pragma unroll
        for (int g = 0; g < 4; g++)
            zz[g] = *(const uint4*)(Zb + ((j[g] << 7) + fo));
        #pragma unroll
        for (int g = 0; g < 4; g++)
            if (32 + g * 8 < c) acc8pk(a, zz[g]);
    }
    for (int b = 64; b < c; b += 32) {   // rare: degree > 64 (csr pad keeps reads safe)
        unsigned j[4];
        #pragma unroll
        for (int g = 0; g < 4; g++) {
            int e = b + g * 8 + eg;
            int er = min(e, c - 1 + 64);             // within padded csr
            unsigned jr = min((unsigned)csr[s + er], un);
            j[g] = (e < c) ? jr : un;
        }
        uint4 zw[4];
        #pragma unroll
        for (int g = 0; g < 4; g++)
            zw[g] = *(const uint4*)(Zb + ((j[g] << 7) + fo));
        #pragma unroll
        for (int g = 0; g < 4; g++)
            if (b + g * 8 < c) acc8pk(a, zw[g]);
    }

    // combine the 8 edge slots (lanes fl, fl+8, ..., fl+56)
    #pragma unroll
    for (int p = 0; p < 4; p++) {
        vfloat2 o;
        o.x = __shfl_xor(a[p].x, 8, 64);  o.y = __shfl_xor(a[p].y, 8, 64);
        a[p] += o;
        o.x = __shfl_xor(a[p].x, 16, 64); o.y = __shfl_xor(a[p].y, 16, 64);
        a[p] += o;
        o.x = __shfl_xor(a[p].x, 32, 64); o.y = __shfl_xor(a[p].y, 32, 64);
        a[p] += o;
    }

    if (eg == 0) {
        float dv = dinv[vs];
        float4 b0 = ((const float4*)bias)[2 * fl];
        float4 b1 = ((const float4*)bias)[2 * fl + 1];
        float r0 = fmaxf(fmaf(a[0].x, dv, b0.x), 0.f);
        float r1 = fmaxf(fmaf(a[0].y, dv, b0.y), 0.f);
        float r2 = fmaxf(fmaf(a[1].x, dv, b0.z), 0.f);
        float r3 = fmaxf(fmaf(a[1].y, dv, b0.w), 0.f);
        float r4 = fmaxf(fmaf(a[2].x, dv, b1.x), 0.f);
        float r5 = fmaxf(fmaf(a[2].y, dv, b1.y), 0.f);
        float r6 = fmaxf(fmaf(a[3].x, dv, b1.z), 0.f);
        float r7 = fmaxf(fmaf(a[3].y, dv, b1.w), 0.f);
        Xout[(size_t)vs * 8 + fl] = make_uint4(pack_bf16(r0, r1), pack_bf16(r2, r3),
                                               pack_bf16(r4, r5), pack_bf16(r6, r7));
    }
}

// ---------------- fused pool (block per graph, batch sorted) + linear + softmax ----------------
__device__ __forceinline__ int lbound(const int* a, int n, int key) {
    int lo = 0, hi = n;
    while (lo < hi) { int mid = (lo + hi) >> 1; if (a[mid] < key) lo = mid + 1; else hi = mid; }
    return lo;
}

__global__ __launch_bounds__(256) void pool_head(const unsigned* __restrict__ x1,
                                                 const unsigned* __restrict__ x2,
                                                 const unsigned* __restrict__ x3,
                                                 const int* __restrict__ batch,
                                                 const float* __restrict__ Wl,
                                                 const float* __restrict__ bl,
                                                 float* __restrict__ out, int n) {
    __shared__ int sb[2];
    __shared__ float red[4][64];
    __shared__ float ps[64];
    __shared__ float lg[10];
    int g = blockIdx.x, t = threadIdx.x;
    int wave = t >> 6, lane = t & 63;
    if (t < 2) sb[t] = lbound(batch, n, g + t);
    __syncthreads();
    int s0 = sb[0], s1 = sb[1];
    // packed loads: 2 nodes per wave per iter, each lane reads one uint (2 bf16)
    int half = lane >> 5, col = lane & 31;
    float a0 = 0.f, a1 = 0.f;
    for (int v = s0 + wave * 2 + half; v < s1; v += 8) {
        size_t off = (size_t)v * 32 + col;
        unsigned u1 = x1[off], u2 = x2[off], u3 = x3[off];
        a0 += (bf16_lo(u1) + bf16_lo(u2)) + bf16_lo(u3);
        a1 += (bf16_hi(u1) + bf16_hi(u2)) + bf16_hi(u3);
    }
    a0 += __shfl_xor(a0, 32, 64);
    a1 += __shfl_xor(a1, 32, 64);
    if (half == 0) { red[wave][2 * col] = a0; red[wave][2 * col + 1] = a1; }
    __syncthreads();
    if (t < 64) {
        int c = s1 - s0;
        float denom = 3.0f * (float)(c > 1 ? c : 1);
        ps[t] = (red[0][t] + red[1][t] + red[2][t] + red[3][t]) / denom;
    }
    __syncthreads();
    if (t < 10) {
        float a = bl[t];
        #pragma unroll 8
        for (int f = 0; f < 64; f++) a += ps[f] * Wl[f * 10 + t];
        lg[t] = a;
    }
    __syncthreads();
    if (t < 10) {
        float mx = -1e30f;
        for (int j = 0; j < 10; j++) mx = fmaxf(mx, lg[j]);
        float e = expf(lg[t] - mx);
        float ss = 0.f;
        for (int j = 0; j < 10; j++) ss += expf(lg[j] - mx);
        out[g * 10 + t] = e / ss;
    }
}

extern "C" void kernel_launch(void* const* d_in, const int* in_sizes, int n_in,
                              void* d_out, int out_size, void* d_ws, size_t ws_size,
                              hipStream_t stream) {
    const float* feats = (const float*)d_in[0];
    const int*   eidx  = (const int*)d_in[1];
    const int*   batch = (const int*)d_in[2];
    const float* W1 = (const float*)d_in[4];
    const float* b1 = (const float*)d_in[5];
    const float* W2 = (const float*)d_in[6];
    const float* b2 = (const float*)d_in[7];
    const float* W3 = (const float*)d_in[8];
    const float* b3 = (const float*)d_in[9];
    const float* Wl = (const float*)d_in[10];
    const float* bl = (const float*)d_in[11];
    float* out = (float*)d_out;

    int n = in_sizes[0] / 128;
    int E = in_sizes[1] / 2;
    int G = out_size / 10;
    int NB = ((n - 1) >> 9) + 1;                   // 512-node buckets
    int per = E / NB;
    int bcap = ALIGN_UP(per + per / 8 + 512, 64);  // mean + >15 sigma margin
    const int* row = eidx;       // destination
    const int* col = eidx + E;   // source

    char* ws = (char*)d_ws;
    size_t o = 0;
    size_t o_fill   = o; o += 2 * NBMAX * 4;                         // fillR | fillC (zeroed)
    size_t o_rowptr = o; o += ALIGN_UP((size_t)n * 4, 256);
    size_t o_indeg  = o; o += ALIGN_UP((size_t)n * 4, 256);
    size_t o_dinv   = o; o += ALIGN_UP((size_t)n * 4, 256);
    size_t o_csr    = o; o += ALIGN_UP((size_t)(E + 64) * 4, 256);   // +64 pad entries = n
    size_t o_z      = o; o += ALIGN_UP(((size_t)n + 1) * 64 * 2, 256); // bf16 Z (+dummy row n)
    size_t o_union  = o;                                             // RB+CB | x1..x3
    size_t rb_bytes = ALIGN_UP((size_t)NB * bcap * 4, 256);
    size_t xl_bytes = ALIGN_UP((size_t)n * 64 * 2, 256);             // bf16 x-layers
    (void)ws_size; (void)n_in;

    int*   fillR = (int*)(ws + o_fill);
    int*   fillC = fillR + NBMAX;
    int*   rowptr = (int*)(ws + o_rowptr);
    int*   indeg  = (int*)(ws + o_indeg);
    float* dinv   = (float*)(ws + o_dinv);
    int*   csr    = (int*)(ws + o_csr);
    unsigned* z   = (unsigned*)(ws + o_z);
    unsigned int*   RB = (unsigned int*)(ws + o_union);
    unsigned short* CB = (unsigned short*)(ws + o_union + rb_bytes);
    unsigned* x1 = (unsigned*)(ws + o_union);                        // overlays RB/CB
    unsigned* x2 = (unsigned*)(ws + o_union + xl_bytes);
    unsigned* x3 = (unsigned*)(ws + o_union + 2 * xl_bytes);

    hipMemsetAsync(ws + o_fill, 0, 2 * NBMAX * 4, stream);

    int gridG = n / 64 + 1;      // gemm: 64 nodes per block; always covers dummy row n
    int gridW = (n + 3) / 4;     // aggregate: one wave per node
    int gridB = (E + CHUNK - 1) / CHUNK;   // bin: 512 blocks (2/CU)

    bin_edges_sort<<<gridB, 1024, 0, stream>>>(row, col, E, NB, bcap, fillR, fillC, RB, CB);
    build_csr_impl<<<NB, 1024, 0, stream>>>(RB, CB, fillR, fillC,
                                            rowptr, indeg, dinv, csr, n, NB, E, bcap);

    // conv1 (RB/CB dead after build_csr; x1 overlays them)
    gemm_mfma<128, false><<<gridG, 256, 0, stream>>>(feats, W1, dinv, z, n);
    aggregate<<<gridW, 256, 0, stream>>>((const uint4*)z, rowptr, indeg, csr, dinv, b1, (uint4*)x1, n);
    // conv2
    gemm_mfma<64, true><<<gridG, 256, 0, stream>>>(x1, W2, dinv, z, n);
    aggregate<<<gridW, 256, 0, stream>>>((const uint4*)z, rowptr, indeg, csr, dinv, b2, (uint4*)x2, n);
    // conv3
    gemm_mfma<64, true><<<gridG, 256, 0, stream>>>(x2, W3, dinv, z, n);
    aggregate<<<gridW, 256, 0, stream>>>((const uint4*)z, rowptr, indeg, csr, dinv, b3, (uint4*)x3, n);

    pool_head<<<G, 256, 0, stream>>>((const unsigned*)x1, (const unsigned*)x2,
                                     (const unsigned*)x3, batch, Wl, bl, out, n);
}

// Round 11
// 375.790 us; speedup vs baseline: 1.8856x; 1.0292x over previous
//
#include <hip/hip_runtime.h>
#include <hip/hip_bf16.h>

// GCN: 3x GCNConv(relu) -> mean over layers -> global mean pool -> linear -> softmax
// N=100000, E=3200000, F_IN=128, F_HID=64, F_OUT=10, G=1000.
//
// out[dst] = dinv[dst] * ( sum_{e: row[e]=dst} z[col[e]] + z[dst] ) + b,
// z = (x @ W) * dinv[:,None], dinv = rsqrt(deg_col + 1).
//
// R21: R20 (MFMA gemms) landed: 424->386.8us. aggregate pinned at its fabric
// floor (3x54.5us). Remaining attackable block = bin+build (~90-120us), and
// build_csr still does RANDOM 4B csr stores into 64KB windows (the write-amp
// mechanism measured in R13/R15). Fix: in-LDS counting sort (R16's trick):
//  - one block per HALF-bucket (256 dst, grid NB*2, static 38KB sortL -> no
//    dynamic-LDS risk, 45KB total).
//  - full 512-bin histogram + scan (global offsets need it), scatter own
//    half into LDS by local dst, emit csr coalesced (full 256B lines).
//  - h==0 block writes rowptr/indeg/dinv; h==1 skips the CB histogram.
// All other kernels byte-identical to R20.

#define ALIGN_UP(x, a) (((x) + (a) - 1) / (a) * (a))
#define NBMAX 256        // max buckets (node id >> 9), supports n <= 131072
#define CHUNK 6250       // max edges per bin block (7 regs/thread, 25KB sort LDS)
#define HBCAP 9600       // half-bucket sort capacity (mean 8192 + ~15 sigma)

typedef float vfloat2 __attribute__((ext_vector_type(2)));
typedef __bf16 bf16v8 __attribute__((ext_vector_type(8)));
typedef float f32x4 __attribute__((ext_vector_type(4)));

__device__ __forceinline__ float bf16_to_f32(unsigned short u) {
    return __uint_as_float(((unsigned)u) << 16);
}
__device__ __forceinline__ float bf16_lo(unsigned u) {
    return __uint_as_float(u << 16);
}
__device__ __forceinline__ float bf16_hi(unsigned u) {
    return __uint_as_float(u & 0xffff0000u);
}
__device__ __forceinline__ unsigned pack_bf16(float a, float b) {
    union { __hip_bfloat16 h; unsigned short u; } ua, ub;
    ua.h = __float2bfloat16(a); ub.h = __float2bfloat16(b);
    return (unsigned)ua.u | ((unsigned)ub.u << 16);
}
__device__ __forceinline__ unsigned short f2bf(float a) {
    union { __hip_bfloat16 h; unsigned short u; } ua;
    ua.h = __float2bfloat16(a);
    return ua.u;
}

// ---------------- Pass A: LDS radix-partition of edges into 512-node buckets ----
// RB entry = (col<<9)|(row&511); CB entry = ushort col&511.
__global__ __launch_bounds__(1024, 8) void bin_edges_sort(const int* __restrict__ row,
                                                          const int* __restrict__ col,
                                                          int E, int NB, int bcap,
                                                          int* __restrict__ fillR,
                                                          int* __restrict__ fillC,
                                                          unsigned int* __restrict__ RB,
                                                          unsigned short* __restrict__ CB) {
    __shared__ unsigned int sortB[CHUNK + 44];     // 25KB; reused as ushort for C
    __shared__ int cntR[NBMAX], cntC[NBMAX];       // histogram, then scatter cursors
    __shared__ int offR[NBMAX + 1], offC[NBMAX + 1];
    __shared__ int baseR[NBMAX], baseC[NBMAX];
    __shared__ int wsumR[4], wsumC[4];

    int t = threadIdx.x;
    for (int i = t; i < NBMAX; i += 1024) { cntR[i] = 0; cntC[i] = 0; }
    __syncthreads();

    int per = (E + gridDim.x - 1) / gridDim.x;     // <= CHUNK by grid sizing
    int e0 = blockIdx.x * per, e1 = min(E, e0 + per);
    int m = e1 - e0;

    // load chunk ONCE into registers (fully unrolled -> static indexing)
    int r[7], c[7];
    #pragma unroll
    for (int k = 0; k < 7; k++) {
        int e = e0 + t + (k << 10);
        bool ok = e < e1;
        r[k] = ok ? row[e] : -1;
        c[k] = ok ? col[e] : 0;
    }
    // histogram
    #pragma unroll
    for (int k = 0; k < 7; k++) {
        if (r[k] >= 0) {
            atomicAdd(&cntR[r[k] >> 9], 1);
            atomicAdd(&cntC[c[k] >> 9], 1);
        }
    }
    __syncthreads();

    // parallel exclusive scans over 256 counters: waves 0-3 -> R, waves 4-7 -> C
    int idx = t & 255;
    bool isR = t < 256, isC = (t >= 256) && (t < 512);
    int val = isR ? cntR[idx] : (isC ? cntC[idx] : 0);
    int lane = t & 63, w4 = (t >> 6) & 3;
    int x = val;
    #pragma unroll
    for (int off = 1; off < 64; off <<= 1) {
        int y = __shfl_up(x, off, 64);
        if (lane >= off) x += y;
    }
    if (isR && lane == 63) wsumR[w4] = x;
    if (isC && lane == 63) wsumC[w4] = x;
    __syncthreads();
    if (isR) {
        int wb = 0;
        #pragma unroll
        for (int i = 0; i < 4; i++) if (i < w4) wb += wsumR[i];
        offR[idx] = wb + x - val;
        if (idx < NB) baseR[idx] = val ? atomicAdd(&fillR[idx], val) : 0;
    }
    if (isC) {
        int wb = 0;
        #pragma unroll
        for (int i = 0; i < 4; i++) if (i < w4) wb += wsumC[i];
        offC[idx] = wb + x - val;
        if (idx < NB) baseC[idx] = val ? atomicAdd(&fillC[idx], val) : 0;
    }
    if (t == 0) offR[NBMAX] = m;
    if (t == 1) offC[NBMAX] = m;
    __syncthreads();
    for (int i = t; i < NBMAX; i += 1024) { cntR[i] = 0; cntC[i] = 0; }  // -> cursors
    __syncthreads();

    // ---- row side: scatter into LDS-sorted order, flush coalesced ----
    #pragma unroll
    for (int k = 0; k < 7; k++) {
        if (r[k] >= 0) {
            int b = r[k] >> 9;
            int p = offR[b] + atomicAdd(&cntR[b], 1);
            sortB[p] = ((unsigned)c[k] << 9) | ((unsigned)r[k] & 511u);
        }
    }
    __syncthreads();
    for (int i = t; i < m; i += 1024) {
        int lo = 0, hi = NB;                       // offR[lo] <= i < offR[hi]
        while (hi - lo > 1) { int mid = (lo + hi) >> 1; if (offR[mid] <= i) lo = mid; else hi = mid; }
        int g = baseR[lo] + (i - offR[lo]);
        if (g < bcap) RB[(size_t)lo * bcap + g] = sortB[i];
    }
    __syncthreads();

    // ---- col side: reuse the buffer as ushort ----
    unsigned short* sortS = (unsigned short*)sortB;
    #pragma unroll
    for (int k = 0; k < 7; k++) {
        if (r[k] >= 0) {
            int b = c[k] >> 9;
            int q = offC[b] + atomicAdd(&cntC[b], 1);
            sortS[q] = (unsigned short)(c[k] & 511);
        }
    }
    __syncthreads();
    for (int i = t; i < m; i += 1024) {
        int lo = 0, hi = NB;
        while (hi - lo > 1) { int mid = (lo + hi) >> 1; if (offC[mid] <= i) lo = mid; else hi = mid; }
        int g = baseC[lo] + (i - offC[lo]);
        if (g < bcap) CB[(size_t)lo * bcap + g] = sortS[i];
    }
}

// ---------------- Pass B: per-HALF-bucket CSR build (256 dst/block) + dinv -----
// grid = NB*2; block bb handles bucket b=bb>>1, half h=bb&1 (locals [256h,256h+256)).
// Full 512-bin histogram + scan (global offsets), LDS counting-sort of own half,
// COALESCED csr emit (kills the random-4B-store write amplification).
__global__ __launch_bounds__(1024) void build_csr_impl(const unsigned int* __restrict__ RB,
                                                       const unsigned short* __restrict__ CB,
                                                       const int* __restrict__ fillR,
                                                       const int* __restrict__ fillC,
                                                       int* __restrict__ rowptr, int* __restrict__ indeg,
                                                       float* __restrict__ dinv, int* __restrict__ csr,
                                                       int n, int NB, int E, int bcap) {
    __shared__ int cnt[512], cnt2[512], start[512], bump[256];
    __shared__ int wsum[8];
    __shared__ int s_base;
    __shared__ unsigned int sortL[HBCAP];
    int bb = blockIdx.x, t = threadIdx.x;
    int b = bb >> 1, h = bb & 1;
    int node0 = b << 9;
    int lo = h << 8;                             // local range start (0 or 256)

    if (bb == 0 && t < 64) csr[E + t] = n;       // pad: unguarded index loads hit zero row

    if (t < 64) {
        int pre = 0;
        for (int j = t; j < b; j += 64) pre += min(fillR[j], bcap);
        #pragma unroll
        for (int off = 32; off; off >>= 1) pre += __shfl_down(pre, off, 64);
        if (t == 0) s_base = pre;
    }
    for (int i = t; i < 512; i += 1024) { cnt[i] = 0; cnt2[i] = 0; }
    if (t < 256) bump[t] = 0;
    __syncthreads();

    int m = min(fillR[b], bcap);
    const unsigned int* src = RB + (size_t)b * bcap;
    for (int i = t; i < m; i += 1024)
        atomicAdd(&cnt[src[i] & 511u], 1);
    if (h == 0) {                                // only h==0 needs dinv inputs
        int mc = min(fillC[b], bcap);
        const unsigned short* sc = CB + (size_t)b * bcap;
        for (int i = t; i < mc; i += 1024)
            atomicAdd(&cnt2[(int)sc[i] & 511], 1);
    }
    __syncthreads();

    // exclusive scan over 512 counters (threads t<512)
    int my = (t < 512) ? cnt[t] : 0;
    int lane = t & 63, w = t >> 6;               // w in 0..7 for t<512
    int x = my;
    #pragma unroll
    for (int off = 1; off < 64; off <<= 1) {
        int y = __shfl_up(x, off, 64);
        if (lane >= off) x += y;
    }
    if (t < 512 && lane == 63) wsum[w] = x;
    __syncthreads();
    int base = s_base;
    if (t < 512) {
        int wb = 0;
        #pragma unroll
        for (int i = 0; i < 8; i++) if (i < w) wb += wsum[i];
        int excl = wb + x - my;
        start[t] = excl;
        int v = node0 + t;
        if (h == 0 && v < n) {
            rowptr[v] = base + excl;
            indeg[v] = my;
            dinv[v] = rsqrtf((float)(cnt2[t] + 1));
        }
    }
    __syncthreads();

    // counting-sort own half into LDS (position = start[local]-start[lo]+bump)
    int s_lo = start[lo];
    for (int i = t; i < m; i += 1024) {
        unsigned en = src[i];
        int local = (int)(en & 511u);
        if ((local >> 8) == h) {
            int p = (start[local] - s_lo) + atomicAdd(&bump[local - lo], 1);
            if (p < HBCAP) sortL[p] = en;
        }
    }
    __syncthreads();

    // coalesced emit: csr[base + start[lo] + i] = col of sorted entry i
    int mh = h ? (m - start[256]) : start[256];  // entries in this half
    mh = min(mh, HBCAP);
    int cbase = base + s_lo;
    for (int i = t; i < mh; i += 1024) {
        int pos = cbase + i;
        if (pos < E) csr[pos] = (int)(sortL[i] >> 9);   // hardening: never OOB
    }
}

// ---------------- dense MFMA: Z(bf16) = (X @ W) * dinv[:,None] ----------------
// Block = 64 nodes x 64 outputs, 4 waves. Wave w owns node rows [16w,16w+16).
// X and W staged to LDS as bf16, XOR-swizzled (^((row&7)<<4)) for conflict-free
// ds_read_b128 fragment loads. Fragments (HW-verified layouts):
//   A: row = lane&15, k = ks*32 + 8*(lane>>4) + i
//   B: col = lane&15, same k               (wt stored transposed: [n][k])
//   D: col = lane&15, row = 4*(lane>>4) + reg
// Epilogue: *dinv, f32 LDS transpose (aliases dead staging), pack bf16 rows.
template <int K, bool BIN>
__global__ __launch_bounds__(256) void gemm_mfma(const void* __restrict__ Xv,
                                                 const float* __restrict__ W,
                                                 const float* __restrict__ dinv,
                                                 unsigned* __restrict__ Z, int n) {
    constexpr int RS = 2 * K;                          // bf16 row stride in bytes
    constexpr int XS = 64 * RS;                        // xs region bytes
    constexpr int SMEM = (2 * XS > 64 * 68 * 4) ? 2 * XS : 64 * 68 * 4;
    __shared__ __align__(16) char sm[SMEM];
    int v0 = blockIdx.x * 64;
    int t = threadIdx.x;

    // ---- stage X (bf16, swizzled) ----
    constexpr int C8 = K / 8;                          // 16B chunks per row
    if (BIN) {
        const unsigned* Xu = (const unsigned*)Xv;      // bf16 rows of K/2 uints
        for (int idx = t; idx < 64 * C8; idx += 256) {
            int i = idx / C8, cp = idx % C8;
            int v = v0 + i;
            uint4 u = (v < n) ? ((const uint4*)(Xu + (size_t)v * (K / 2)))[cp]
                              : make_uint4(0, 0, 0, 0);
            int d = (i * RS + cp * 16) ^ ((i & 7) << 4);
            *(uint4*)(sm + d) = u;
        }
    } else {
        const float* X = (const float*)Xv;
        for (int idx = t; idx < 64 * C8; idx += 256) {
            int i = idx / C8, cp = idx % C8;
            int v = v0 + i;
            float4 f0 = make_float4(0.f, 0.f, 0.f, 0.f), f1 = f0;
            if (v < n) {
                f0 = ((const float4*)(X + (size_t)v * K))[cp * 2];
                f1 = ((const float4*)(X + (size_t)v * K))[cp * 2 + 1];
            }
            uint4 u;
            u.x = pack_bf16(f0.x, f0.y); u.y = pack_bf16(f0.z, f0.w);
            u.z = pack_bf16(f1.x, f1.y); u.w = pack_bf16(f1.z, f1.w);
            int d = (i * RS + cp * 16) ^ ((i & 7) << 4);
            *(uint4*)(sm + d) = u;
        }
    }
    // ---- stage W transposed (wt[n][k], bf16, swizzled) ----
    {
        int nn = t & 63, k0 = t >> 6;                  // k0 in 0..3
        for (int k = k0; k < K; k += 4) {
            unsigned short wb = f2bf(W[k * 64 + nn]);
            int d = (XS + nn * RS + k * 2) ^ ((nn & 7) << 4);
            *(unsigned short*)(sm + d) = wb;
        }
    }
    __syncthreads();

    int lane = t & 63;
    int wave = __builtin_amdgcn_readfirstlane(t >> 6);
    int m0 = wave * 16;
    int lm = lane & 15, kg = lane >> 4;

    f32x4 acc[4];
    #pragma unroll
    for (int tl = 0; tl < 4; tl++) acc[tl] = f32x4{0.f, 0.f, 0.f, 0.f};

    #pragma unroll
    for (int ks = 0; ks < K / 32; ks++) {
        int ao = ((m0 + lm) * RS + ks * 64 + kg * 16) ^ ((lm & 7) << 4);
        bf16v8 a = *(const bf16v8*)(sm + ao);
        #pragma unroll
        for (int tl = 0; tl < 4; tl++) {
            int bo = (XS + (16 * tl + lm) * RS + ks * 64 + kg * 16) ^ ((lm & 7) << 4);
            bf16v8 b = *(const bf16v8*)(sm + bo);
            acc[tl] = __builtin_amdgcn_mfma_f32_16x16x32_bf16(a, b, acc[tl], 0, 0, 0);
        }
    }

    // per-reg dinv (node rows m0 + 4*kg + i)
    float dvr[4];
    #pragma unroll
    for (int i = 0; i < 4; i++) {
        int vi = v0 + m0 + 4 * kg + i;
        dvr[i] = (vi < n) ? dinv[vi] : 0.f;
    }

    __syncthreads();                                   // staging dead; reuse as f32 out
    float* outf = (float*)sm;
    #pragma unroll
    for (int tl = 0; tl < 4; tl++)
        #pragma unroll
        for (int i = 0; i < 4; i++)
            outf[(m0 + 4 * kg + i) * 68 + 16 * tl + lm] = acc[tl][i] * dvr[i];
    __syncthreads();

    // pack coalesced bf16 rows: Z[v][c] = (f[2c], f[2c+1])
    for (int idx = t; idx < 2048; idx += 256) {
        int i = idx >> 5, c = idx & 31;
        int v = v0 + i;
        if (v <= n)                                    // row n = zeros (dummy)
            Z[(size_t)v * 32 + c] = pack_bf16(outf[i * 68 + 2 * c], outf[i * 68 + 2 * c + 1]);
    }
}

// ---------------- sparse aggregate + bias + relu (bf16 gather -> bf16 out) ----------------
// One wave per dst node. 8 lanes per edge (dwordx4 = 8 features), one wave
// VMEM instr = 8 edges = 8 x 128B lines. At the L2-miss fabric floor
// (~160MB @ ~3.2TB/s) -- measured best structure (R16/R19/R20).
__device__ __forceinline__ void acc8pk(vfloat2 a[4], uint4 z) {
    vfloat2 t0 = { bf16_lo(z.x), bf16_hi(z.x) };
    vfloat2 t1 = { bf16_lo(z.y), bf16_hi(z.y) };
    vfloat2 t2 = { bf16_lo(z.z), bf16_hi(z.z) };
    vfloat2 t3 = { bf16_lo(z.w), bf16_hi(z.w) };
    a[0] += t0; a[1] += t1; a[2] += t2; a[3] += t3;
}

__global__ __launch_bounds__(256) void aggregate(const uint4* __restrict__ Z4,
                                                 const int* __restrict__ rowptr,
                                                 const int* __restrict__ indeg,
                                                 const int* __restrict__ csr,
                                                 const float* __restrict__ dinv,
                                                 const float* __restrict__ bias,
                                                 uint4* __restrict__ Xout, int n) {
    int wave = threadIdx.x >> 6;
    int lane = threadIdx.x & 63;
    int v = blockIdx.x * 4 + wave;
    if (v >= n) return;
    int vs = __builtin_amdgcn_readfirstlane(v);
    int eg = lane >> 3;                      // edge slot 0..7
    int fl = lane & 7;                       // feature octet (features 8fl..8fl+7)
    unsigned un = (unsigned)n;               // dummy zero row index (also clamp)
    const char* Zb = (const char*)Z4;
    unsigned fo = (unsigned)(fl << 4);       // feature byte offset within row

    int s = rowptr[vs], c = indeg[vs];       // scalar (vs uniform)

    vfloat2 a[4];
    {
        uint4 sv = make_uint4(0u, 0u, 0u, 0u);
        if (eg == 0) sv = *(const uint4*)(Zb + (((unsigned)vs << 7) + fo));  // self-loop
        a[0] = vfloat2{ bf16_lo(sv.x), bf16_hi(sv.x) };
        a[1] = vfloat2{ bf16_lo(sv.y), bf16_hi(sv.y) };
        a[2] = vfloat2{ bf16_lo(sv.z), bf16_hi(sv.z) };
        a[3] = vfloat2{ bf16_lo(sv.w), bf16_hi(sv.w) };
    }

    // chunk [0,32): 4 index loads (unguarded, pad-safe) -> 4 gathers in flight,
    // acc skipped per dead group by wave-uniform branch (c scalar).
    {
        unsigned j[4];
        #pragma unroll
        for (int g = 0; g < 4; g++) {
            int e = g * 8 + eg;
            unsigned jr = min((unsigned)csr[s + e], un);
            j[g] = (e < c) ? jr : un;
        }
        uint4 zz[4];
        #pragma unroll
        for (int g = 0; g < 4; g++)
            zz[g] = *(const uint4*)(Zb + ((j[g] << 7) + fo));
        #pragma unroll
        for (int g = 0; g < 4; g++)
            if (g * 8 < c) acc8pk(a, zz[g]);
    }
    if (c > 32) {   // chunk [32,64): skipped entirely for 54% of nodes
        unsigned j[4];
        #pragma unroll
        for (int g = 0; g < 4; g++) {
            int e = 32 + g * 8 + eg;
            unsigned jr = min((unsigned)csr[s + e], un);
            j[g] = (e < c) ? jr : un;
        }
        uint4 zz[4];
        #pragma unroll
        for (int g = 0; g < 4; g++)
            zz[g] = *(const uint4*)(Zb + ((j[g] << 7) + fo));
        #pragma unroll
        for (int g = 0; g < 4; g++)
            if (32 + g * 8 < c) acc8pk(a, zz[g]);
    }
    for (int b = 64; b < c; b += 32) {   // rare: degree > 64 (csr pad keeps reads safe)
        unsigned j[4];
        #pragma unroll
        for (int g = 0; g < 4; g++) {
            int e = b + g * 8 + eg;
            int er = min(e, c - 1 + 64);             // within padded csr
            unsigned jr = min((unsigned)csr[s + er], un);
            j[g] = (e < c) ? jr : un;
        }
        uint4 zw[4];
        #pragma unroll
        for (int g = 0; g < 4; g++)
            zw[g] = *(const uint4*)(Zb + ((j[g] << 7) + fo));
        #pragma unroll
        for (int g = 0; g < 4; g++)
            if (b + g * 8 < c) acc8pk(a, zw[g]);
    }

    // combine the 8 edge slots (lanes fl, fl+8, ..., fl+56)
    #pragma unroll
    for (int p = 0; p < 4; p++) {
        vfloat2 o;
        o.x = __shfl_xor(a[p].x, 8, 64);  o.y = __shfl_xor(a[p].y, 8, 64);
        a[p] += o;
        o.x = __shfl_xor(a[p].x, 16, 64); o.y = __shfl_xor(a[p].y, 16, 64);
        a[p] += o;
        o.x = __shfl_xor(a[p].x, 32, 64); o.y = __shfl_xor(a[p].y, 32, 64);
        a[p] += o;
    }

    if (eg == 0) {
        float dv = dinv[vs];
        float4 b0 = ((const float4*)bias)[2 * fl];
        float4 b1 = ((const float4*)bias)[2 * fl + 1];
        float r0 = fmaxf(fmaf(a[0].x, dv, b0.x), 0.f);
        float r1 = fmaxf(fmaf(a[0].y, dv, b0.y), 0.f);
        float r2 = fmaxf(fmaf(a[1].x, dv, b0.z), 0.f);
        float r3 = fmaxf(fmaf(a[1].y, dv, b0.w), 0.f);
        float r4 = fmaxf(fmaf(a[2].x, dv, b1.x), 0.f);
        float r5 = fmaxf(fmaf(a[2].y, dv, b1.y), 0.f);
        float r6 = fmaxf(fmaf(a[3].x, dv, b1.z), 0.f);
        float r7 = fmaxf(fmaf(a[3].y, dv, b1.w), 0.f);
        Xout[(size_t)vs * 8 + fl] = make_uint4(pack_bf16(r0, r1), pack_bf16(r2, r3),
                                               pack_bf16(r4, r5), pack_bf16(r6, r7));
    }
}

// ---------------- fused pool (block per graph, batch sorted) + linear + softmax ----------------
__device__ __forceinline__ int lbound(const int* a, int n, int key) {
    int lo = 0, hi = n;
    while (lo < hi) { int mid = (lo + hi) >> 1; if (a[mid] < key) lo = mid + 1; else hi = mid; }
    return lo;
}

__global__ __launch_bounds__(256) void pool_head(const unsigned* __restrict__ x1,
                                                 const unsigned* __restrict__ x2,
                                                 const unsigned* __restrict__ x3,
                                                 const int* __restrict__ batch,
                                                 const float* __restrict__ Wl,
                                                 const float* __restrict__ bl,
                                                 float* __restrict__ out, int n) {
    __shared__ int sb[2];
    __shared__ float red[4][64];
    __shared__ float ps[64];
    __shared__ float lg[10];
    int g = blockIdx.x, t = threadIdx.x;
    int wave = t >> 6, lane = t & 63;
    if (t < 2) sb[t] = lbound(batch, n, g + t);
    __syncthreads();
    int s0 = sb[0], s1 = sb[1];
    // packed loads: 2 nodes per wave per iter, each lane reads one uint (2 bf16)
    int half = lane >> 5, col = lane & 31;
    float a0 = 0.f, a1 = 0.f;
    for (int v = s0 + wave * 2 + half; v < s1; v += 8) {
        size_t off = (size_t)v * 32 + col;
        unsigned u1 = x1[off], u2 = x2[off], u3 = x3[off];
        a0 += (bf16_lo(u1) + bf16_lo(u2)) + bf16_lo(u3);
        a1 += (bf16_hi(u1) + bf16_hi(u2)) + bf16_hi(u3);
    }
    a0 += __shfl_xor(a0, 32, 64);
    a1 += __shfl_xor(a1, 32, 64);
    if (half == 0) { red[wave][2 * col] = a0; red[wave][2 * col + 1] = a1; }
    __syncthreads();
    if (t < 64) {
        int c = s1 - s0;
        float denom = 3.0f * (float)(c > 1 ? c : 1);
        ps[t] = (red[0][t] + red[1][t] + red[2][t] + red[3][t]) / denom;
    }
    __syncthreads();
    if (t < 10) {
        float a = bl[t];
        #pragma unroll 8
        for (int f = 0; f < 64; f++) a += ps[f] * Wl[f * 10 + t];
        lg[t] = a;
    }
    __syncthreads();
    if (t < 10) {
        float mx = -1e30f;
        for (int j = 0; j < 10; j++) mx = fmaxf(mx, lg[j]);
        float e = expf(lg[t] - mx);
        float ss = 0.f;
        for (int j = 0; j < 10; j++) ss += expf(lg[j] - mx);
        out[g * 10 + t] = e / ss;
    }
}

extern "C" void kernel_launch(void* const* d_in, const int* in_sizes, int n_in,
                              void* d_out, int out_size, void* d_ws, size_t ws_size,
                              hipStream_t stream) {
    const float* feats = (const float*)d_in[0];
    const int*   eidx  = (const int*)d_in[1];
    const int*   batch = (const int*)d_in[2];
    const float* W1 = (const float*)d_in[4];
    const float* b1 = (const float*)d_in[5];
    const float* W2 = (const float*)d_in[6];
    const float* b2 = (const float*)d_in[7];
    const float* W3 = (const float*)d_in[8];
    const float* b3 = (const float*)d_in[9];
    const float* Wl = (const float*)d_in[10];
    const float* bl = (const float*)d_in[11];
    float* out = (float*)d_out;

    int n = in_sizes[0] / 128;
    int E = in_sizes[1] / 2;
    int G = out_size / 10;
    int NB = ((n - 1) >> 9) + 1;                   // 512-node buckets
    int per = E / NB;
    int bcap = ALIGN_UP(per + per / 8 + 512, 64);  // mean + >15 sigma margin
    const int* row = eidx;       // destination
    const int* col = eidx + E;   // source

    char* ws = (char*)d_ws;
    size_t o = 0;
    size_t o_fill   = o; o += 2 * NBMAX * 4;                         // fillR | fillC (zeroed)
    size_t o_rowptr = o; o += ALIGN_UP((size_t)n * 4, 256);
    size_t o_indeg  = o; o += ALIGN_UP((size_t)n * 4, 256);
    size_t o_dinv   = o; o += ALIGN_UP((size_t)n * 4, 256);
    size_t o_csr    = o; o += ALIGN_UP((size_t)(E + 64) * 4, 256);   // +64 pad entries = n
    size_t o_z      = o; o += ALIGN_UP(((size_t)n + 1) * 64 * 2, 256); // bf16 Z (+dummy row n)
    size_t o_union  = o;                                             // RB+CB | x1..x3
    size_t rb_bytes = ALIGN_UP((size_t)NB * bcap * 4, 256);
    size_t xl_bytes = ALIGN_UP((size_t)n * 64 * 2, 256);             // bf16 x-layers
    (void)ws_size; (void)n_in;

    int*   fillR = (int*)(ws + o_fill);
    int*   fillC = fillR + NBMAX;
    int*   rowptr = (int*)(ws + o_rowptr);
    int*   indeg  = (int*)(ws + o_indeg);
    float* dinv   = (float*)(ws + o_dinv);
    int*   csr    = (int*)(ws + o_csr);
    unsigned* z   = (unsigned*)(ws + o_z);
    unsigned int*   RB = (unsigned int*)(ws + o_union);
    unsigned short* CB = (unsigned short*)(ws + o_union + rb_bytes);
    unsigned* x1 = (unsigned*)(ws + o_union);                        // overlays RB/CB
    unsigned* x2 = (unsigned*)(ws + o_union + xl_bytes);
    unsigned* x3 = (unsigned*)(ws + o_union + 2 * xl_bytes);

    hipMemsetAsync(ws + o_fill, 0, 2 * NBMAX * 4, stream);

    int gridG = n / 64 + 1;      // gemm: 64 nodes per block; always covers dummy row n
    int gridW = (n + 3) / 4;     // aggregate: one wave per node
    int gridB = (E + CHUNK - 1) / CHUNK;   // bin: 512 blocks (2/CU)

    bin_edges_sort<<<gridB, 1024, 0, stream>>>(row, col, E, NB, bcap, fillR, fillC, RB, CB);
    build_csr_impl<<<NB * 2, 1024, 0, stream>>>(RB, CB, fillR, fillC,
                                                rowptr, indeg, dinv, csr, n, NB, E, bcap);

    // conv1 (RB/CB dead after build_csr; x1 overlays them)
    gemm_mfma<128, false><<<gridG, 256, 0, stream>>>(feats, W1, dinv, z, n);
    aggregate<<<gridW, 256, 0, stream>>>((const uint4*)z, rowptr, indeg, csr, dinv, b1, (uint4*)x1, n);
    // conv2
    gemm_mfma<64, true><<<gridG, 256, 0, stream>>>(x1, W2, dinv, z, n);
    aggregate<<<gridW, 256, 0, stream>>>((const uint4*)z, rowptr, indeg, csr, dinv, b2, (uint4*)x2, n);
    // conv3
    gemm_mfma<64, true><<<gridG, 256, 0, stream>>>(x2, W3, dinv, z, n);
    aggregate<<<gridW, 256, 0, stream>>>((const uint4*)z, rowptr, indeg, csr, dinv, b3, (uint4*)x3, n);

    pool_head<<<G, 256, 0, stream>>>((const unsigned*)x1, (const unsigned*)x2,
                                     (const unsigned*)x3, batch, Wl, bl, out, n);
}